// Round 1
// 721.568 us; speedup vs baseline: 1.0376x; 1.0376x over previous
//
#include <hip/hip_runtime.h>

#define B_    16
#define CDIM  512
#define NSP   4096
#define GK    512
#define SQRTC 22.62741699796952f
#define CTX_SLICES 8

typedef __attribute__((ext_vector_type(4))) float f32x4;
typedef __attribute__((ext_vector_type(8))) short s16x8;
typedef __attribute__((ext_vector_type(4))) unsigned short u16x4;
typedef __attribute__((ext_vector_type(8))) unsigned short u16x8;

__device__ __forceinline__ float bf2f(unsigned short u) {
    union { unsigned int i; float f; } v; v.i = ((unsigned int)u) << 16; return v.f;
}
__device__ __forceinline__ unsigned short f2bf(float f) {
    union { float fl; unsigned int i; } v; v.fl = f;
    unsigned int r = v.i + 0x7FFFu + ((v.i >> 16) & 1u);
    return (unsigned short)(r >> 16);
}

// async global -> LDS, 16B per lane. LDS dest must be wave-uniform base; HW adds lane*16.
__device__ __forceinline__ void gload16(const unsigned short* g, unsigned short* l) {
    __builtin_amdgcn_global_load_lds(
        (const __attribute__((address_space(1))) unsigned int*)g,
        (__attribute__((address_space(3))) unsigned int*)l,
        16, 0, 0);
}

// ---------------- fp32 -> bf16 weight conversion
__global__ __launch_bounds__(256) void convert_k(const float* __restrict__ in,
                                                 unsigned short* __restrict__ out, int n4) {
    int i = blockIdx.x * 256 + threadIdx.x;
    if (i >= n4) return;
    f32x4 v = *(const f32x4*)(in + (long)i * 4);
    u16x4 o;
    #pragma unroll
    for (int s = 0; s < 4; ++s) o[s] = f2bf(v[s]);
    *(u16x4*)(out + (long)i * 4) = o;
}

// ---------------- inv[b,n] = sqrt(512)/max(||x[b,:,n]||,eps), x fp32 [b,c,n]
__global__ __launch_bounds__(256) void inv_stats_x_k(const float* __restrict__ x,
                                                     float* __restrict__ inv) {
    int p = blockIdx.x * 256 + threadIdx.x;
    int b = p >> 12, n = p & 4095;
    const float* xb = x + (long)b * CDIM * NSP + n;
    float ss = 0.f;
    for (int c = 0; c < CDIM; ++c) { float v = xb[(long)c * NSP]; ss += v * v; }
    inv[p] = SQRTC / fmaxf(sqrtf(ss), 1e-12f);
}

// ---------------- inv over internal bf16 y [b,c,n]
__global__ __launch_bounds__(256) void inv_stats_y_k(const unsigned short* __restrict__ y,
                                                     float* __restrict__ inv) {
    int p = blockIdx.x * 256 + threadIdx.x;
    int b = p >> 12, n = p & 4095;
    const unsigned short* yb = y + (long)b * CDIM * NSP + n;
    float ss = 0.f;
    for (int c = 0; c < CDIM; ++c) { float v = bf2f(yb[(long)c * NSP]); ss += v * v; }
    inv[p] = SQRTC / fmaxf(sqrtf(ss), 1e-12f);
}

// ---------------- xn_t[b][n][c] = x[b][c][n]*inv1[b,n]*g1[c]  (fp32 in, bf16 out, transpose)
__global__ __launch_bounds__(256) void xnt_kernel(const float* __restrict__ x,
                                                  const float* __restrict__ g1,
                                                  const float* __restrict__ inv,
                                                  unsigned short* __restrict__ xnt) {
    alignas(16) __shared__ float tile[64 * 68];
    int n0 = blockIdx.x * 64, c0 = blockIdx.y * 64, b = blockIdx.z;
    int t = threadIdx.x;
    #pragma unroll
    for (int it = 0; it < 4; ++it) {
        int idx = it * 256 + t;
        int r = idx >> 4, c4 = (idx & 15) * 4;          // r = c-row, c4 = n-col
        f32x4 v = *(const f32x4*)(x + (long)(b * CDIM + c0 + r) * NSP + n0 + c4);
        *(f32x4*)(tile + r * 68 + c4) = v;
    }
    __syncthreads();
    #pragma unroll
    for (int it = 0; it < 4; ++it) {
        int idx = it * 256 + t;
        int nr = idx >> 4, cc = (idx & 15) * 4;         // nr = n-row, cc = c-col
        float s = inv[b * NSP + n0 + nr];
        u16x4 o;
        #pragma unroll
        for (int si = 0; si < 4; ++si)
            o[si] = f2bf(tile[(cc + si) * 68 + nr] * s * g1[c0 + cc + si]);
        *(u16x4*)(xnt + (long)(b * NSP + n0 + nr) * CDIM + c0 + cc) = o;
    }
}

// ---------------- MFMA GEMM: C[b][m][n] = A[m][:].Bt[b][n][:] (+bias fp32), bf16 in/out
// LDS staging via global_load_lds width=16 (dest byte addr = idx*16 is linear in thread idx).
__global__ __launch_bounds__(256, 2) void gemm_bt_kernel(
        const unsigned short* __restrict__ A, const unsigned short* __restrict__ Bt,
        unsigned short* __restrict__ C, const float* __restrict__ bias,
        long bt_bstride, long c_bstride) {
    alignas(16) __shared__ unsigned short As[128 * 32];
    alignas(16) __shared__ unsigned short Bs[128 * 32];
    const int t = threadIdx.x, wave = t >> 6, lane = t & 63;
    const int l15 = lane & 15, quad = lane >> 4;
    const int wm = (wave >> 1) * 64, wn = (wave & 1) * 64;
    const int m0 = blockIdx.y * 128, n0 = blockIdx.x * 128, b = blockIdx.z;
    const unsigned short* Bb = Bt + (long)b * bt_bstride;
    unsigned short* Cb = C + (long)b * c_bstride;

    f32x4 acc[4][4] = {};
    for (int k0 = 0; k0 < GK; k0 += 32) {
        #pragma unroll
        for (int it = 0; it < 2; ++it) {
            int idx = it * 256 + t;                       // 0..511, 16B each
            int row = idx >> 2, c8 = (idx & 3) * 8;
            int wbase = (it * 256 + (t & 192)) * 8;       // wave-uniform LDS base (shorts)
            gload16(A  + (long)(m0 + row) * GK + k0 + c8, As + wbase);
            gload16(Bb + (long)(n0 + row) * GK + k0 + c8, Bs + wbase);
        }
        __syncthreads();
        s16x8 af[4], bfr[4];
        #pragma unroll
        for (int i = 0; i < 4; ++i) af[i]  = *(const s16x8*)(As + (wm + i * 16 + l15) * 32 + quad * 8);
        #pragma unroll
        for (int j = 0; j < 4; ++j) bfr[j] = *(const s16x8*)(Bs + (wn + j * 16 + l15) * 32 + quad * 8);
        #pragma unroll
        for (int i = 0; i < 4; ++i)
            #pragma unroll
            for (int j = 0; j < 4; ++j)
                acc[i][j] = __builtin_amdgcn_mfma_f32_16x16x32_bf16(af[i], bfr[j], acc[i][j], 0, 0, 0);
        __syncthreads();
    }
    #pragma unroll
    for (int i = 0; i < 4; ++i)
        #pragma unroll
        for (int r = 0; r < 4; ++r) {
            int row = m0 + wm + i * 16 + quad * 4 + r;
            float bv = bias ? bias[row] : 0.0f;
            #pragma unroll
            for (int j = 0; j < 4; ++j) {
                int col = n0 + wn + j * 16 + l15;
                Cb[(long)row * NSP + col] = f2bf(acc[i][j][r] + bv);
            }
        }
}

// ---------------- k softmax stats per (b,row): max, 1/sum(exp). Single global pass,
// values held in registers, shfl-based reduction (2 barriers instead of 16).
__global__ __launch_bounds__(256) void kstats_k(const unsigned short* __restrict__ kv,
                                                float* __restrict__ kst) {
    __shared__ float red[8];
    int row = blockIdx.x, b = blockIdx.y, t = threadIdx.x;
    int wave = t >> 6, lane = t & 63;
    const unsigned short* base = kv + ((long)b * 1024 + row) * NSP;
    float v[16];
    u16x8 a0 = *(const u16x8*)(base + t * 16);
    u16x8 a1 = *(const u16x8*)(base + t * 16 + 8);
    #pragma unroll
    for (int e = 0; e < 8; ++e) { v[e] = bf2f(a0[e]); v[8 + e] = bf2f(a1[e]); }
    float mx = v[0];
    #pragma unroll
    for (int e = 1; e < 16; ++e) mx = fmaxf(mx, v[e]);
    #pragma unroll
    for (int off = 32; off; off >>= 1) mx = fmaxf(mx, __shfl_xor(mx, off));
    if (lane == 0) red[wave] = mx;
    __syncthreads();
    mx = fmaxf(fmaxf(red[0], red[1]), fmaxf(red[2], red[3]));
    float sm = 0.f;
    #pragma unroll
    for (int e = 0; e < 16; ++e) sm += __expf(v[e] - mx);
    #pragma unroll
    for (int off = 32; off; off >>= 1) sm += __shfl_xor(sm, off);
    if (lane == 0) red[4 + wave] = sm;
    __syncthreads();
    if (t == 0) {
        float s = red[4] + red[5] + red[6] + red[7];
        kst[((long)b * 512 + row) * 2]     = mx;
        kst[((long)b * 512 + row) * 2 + 1] = 1.f / s;
    }
}

// ---------------- ctxP[slice][bh][e*64+d] = sum_{n in slice} khat[d,n]*v[e,n]
// (MFMA, exp fused). Cross-wave reduction in LDS (swizzled atomicAdd), plain stores.
// NO global atomics.
__global__ __launch_bounds__(256) void context_kernel(const unsigned short* __restrict__ kv,
                                                      const float* __restrict__ kst,
                                                      float* __restrict__ ctxP) {
    __shared__ float sctx[4096];                          // 16 KB
    int bh = blockIdx.x, b = bh >> 3, h = bh & 7;
    int t = threadIdx.x, wave = t >> 6, lane = t & 63, l15 = lane & 15, quad = lane >> 4;
    int nbase = blockIdx.y * (NSP / CTX_SLICES) + wave * (NSP / CTX_SLICES / 4);
    const unsigned short* kp = kv + ((long)b * 1024 + h * 64) * NSP;
    const unsigned short* vp = kv + ((long)b * 1024 + 512 + h * 64) * NSP;
    float mx[4], rs[4];
    #pragma unroll
    for (int i = 0; i < 4; ++i) {
        int d = i * 16 + l15;
        mx[i] = kst[((long)b * 512 + h * 64 + d) * 2];
        rs[i] = kst[((long)b * 512 + h * 64 + d) * 2 + 1];
    }
    // zero LDS accumulator
    #pragma unroll
    for (int it = 0; it < 4; ++it)
        *(f32x4*)(sctx + it * 1024 + t * 4) = (f32x4){0.f, 0.f, 0.f, 0.f};

    f32x4 acc[4][4] = {};
    for (int ks = 0; ks < (NSP / CTX_SLICES / 4) / 32; ++ks) {
        int n0 = nbase + ks * 32 + quad * 8;
        s16x8 af[4], bfr[4];
        #pragma unroll
        for (int i = 0; i < 4; ++i) {
            u16x8 u = *(const u16x8*)(kp + (long)(i * 16 + l15) * NSP + n0);
            s16x8 a;
            #pragma unroll
            for (int e = 0; e < 8; ++e)
                a[e] = (short)f2bf(__expf(bf2f(u[e]) - mx[i]) * rs[i]);
            af[i] = a;
        }
        #pragma unroll
        for (int j = 0; j < 4; ++j)
            bfr[j] = *(const s16x8*)(vp + (long)(j * 16 + l15) * NSP + n0);
        #pragma unroll
        for (int i = 0; i < 4; ++i)
            #pragma unroll
            for (int j = 0; j < 4; ++j)
                acc[i][j] = __builtin_amdgcn_mfma_f32_16x16x32_bf16(af[i], bfr[j], acc[i][j], 0, 0, 0);
    }
    __syncthreads();
    // cross-wave reduce via LDS atomics; XOR-swizzle col with row bits to spread banks
    #pragma unroll
    for (int i = 0; i < 4; ++i)
        #pragma unroll
        for (int j = 0; j < 4; ++j) {
            int row = j * 16 + l15;
            #pragma unroll
            for (int r = 0; r < 4; ++r) {
                int col = i * 16 + quad * 4 + r;
                atomicAdd(&sctx[row * 64 + (col ^ ((row & 7) << 3))], acc[i][j][r]);
            }
        }
    __syncthreads();
    float* cp = ctxP + ((long)blockIdx.y * 128 + bh) * 4096;
    #pragma unroll
    for (int it = 0; it < 4; ++it) {
        int o = it * 1024 + t * 4;
        int row = o >> 6, col = o & 63;
        *(f32x4*)(cp + o) = *(const f32x4*)(sctx + row * 64 + (col ^ ((row & 7) << 3)));
    }
}

// ---------------- ctxT = sum over slices of ctxP
__global__ __launch_bounds__(256) void ctxreduce_k(const float* __restrict__ ctxP,
                                                   float* __restrict__ ctxT) {
    long i = ((long)blockIdx.x * 256 + threadIdx.x) * 4;
    f32x4 s = *(const f32x4*)(ctxP + i);
    #pragma unroll
    for (int sl = 1; sl < CTX_SLICES; ++sl) {
        f32x4 v = *(const f32x4*)(ctxP + (long)sl * 128 * 4096 + i);
        s += v;
    }
    *(f32x4*)(ctxT + i) = s;
}

// ---------------- qhatT[bh][n][d] = softmax_d(q)[d,n]*0.125  (bf16, d contiguous)
__global__ __launch_bounds__(256) void qhat_kernel(const unsigned short* __restrict__ qbuf,
                                                   unsigned short* __restrict__ qhatT) {
    alignas(16) __shared__ unsigned short tile[64 * 256];
    int n0 = blockIdx.x * 256, h = blockIdx.y, b = blockIdx.z, t = threadIdx.x;
    const unsigned short* qp = qbuf + ((long)b * 512 + h * 64) * NSP;
    #pragma unroll
    for (int it = 0; it < 16; ++it) {
        int idx = it * 256 + t;
        int d = idx >> 6, c4 = (idx & 63) * 4;
        *(u16x4*)(tile + d * 256 + c4) = *(const u16x4*)(qp + (long)d * NSP + n0 + c4);
    }
    __syncthreads();
    float mx = -3.4e38f;
    for (int d = 0; d < 64; ++d) mx = fmaxf(mx, bf2f(tile[d * 256 + t]));
    float sum = 0.f;
    for (int d = 0; d < 64; ++d) sum += __expf(bf2f(tile[d * 256 + t]) - mx);
    float rsc = 0.125f / sum;
    unsigned short* op = qhatT + ((long)(b * 8 + h) * NSP + n0 + t) * 64;
    #pragma unroll
    for (int d4 = 0; d4 < 16; ++d4) {
        u16x4 o;
        #pragma unroll
        for (int si = 0; si < 4; ++si)
            o[si] = f2bf(__expf(bf2f(tile[(d4 * 4 + si) * 256 + t]) - mx) * rsc);
        *(u16x4*)(op + d4 * 4) = o;
    }
}

// ---------------- attnT[b][n][h*64+e] = sum_d ctxT[e][d]*qhatT[n][d]   (MFMA)
__global__ __launch_bounds__(256) void attnout_kernel(const float* __restrict__ ctxT,
                                                      const unsigned short* __restrict__ qhatT,
                                                      unsigned short* __restrict__ attnT) {
    int bh = blockIdx.x, b = bh >> 3, h = bh & 7;
    int t = threadIdx.x, wave = t >> 6, lane = t & 63, l15 = lane & 15, quad = lane >> 4;
    int n0 = blockIdx.y * 256 + wave * 64;
    const float* cb = ctxT + (long)bh * 4096;
    s16x8 af[2][4];
    #pragma unroll
    for (int ks = 0; ks < 2; ++ks)
        #pragma unroll
        for (int i = 0; i < 4; ++i) {
            const float* src = cb + (i * 16 + l15) * 64 + ks * 32 + quad * 8;
            s16x8 a;
            #pragma unroll
            for (int e = 0; e < 8; ++e) a[e] = (short)f2bf(src[e]);
            af[ks][i] = a;
        }
    f32x4 acc[4][4] = {};
    const unsigned short* qb = qhatT + (long)bh * NSP * 64;
    #pragma unroll
    for (int ks = 0; ks < 2; ++ks) {
        s16x8 bfr[4];
        #pragma unroll
        for (int j = 0; j < 4; ++j)
            bfr[j] = *(const s16x8*)(qb + (long)(n0 + j * 16 + l15) * 64 + ks * 32 + quad * 8);
        #pragma unroll
        for (int i = 0; i < 4; ++i)
            #pragma unroll
            for (int j = 0; j < 4; ++j)
                acc[i][j] = __builtin_amdgcn_mfma_f32_16x16x32_bf16(af[ks][i], bfr[j], acc[i][j], 0, 0, 0);
    }
    #pragma unroll
    for (int i = 0; i < 4; ++i)
        #pragma unroll
        for (int j = 0; j < 4; ++j) {
            int n = n0 + j * 16 + l15;
            u16x4 o;
            #pragma unroll
            for (int r = 0; r < 4; ++r) o[r] = f2bf(acc[i][j][r]);
            *(u16x4*)(attnT + ((long)b * NSP + n) * CDIM + h * 64 + i * 16 + quad * 4) = o;
        }
}

// ---------------- out fp32 = y_bf16 * inv2[b,n] * g2[c]
__global__ __launch_bounds__(256) void final_kernel(const unsigned short* __restrict__ y,
                                                    const float* __restrict__ g2,
                                                    const float* __restrict__ inv2,
                                                    float* __restrict__ out) {
    long flat = ((long)blockIdx.x * 256 + threadIdx.x) * 4;
    int b = (int)(flat >> 21);
    int rem = (int)(flat & ((1 << 21) - 1));
    int c = rem >> 12, n = rem & 4095;
    u16x4 u = *(const u16x4*)(y + flat);
    f32x4 iv = *(const f32x4*)(inv2 + b * NSP + n);
    float g = g2[c];
    f32x4 ov;
    #pragma unroll
    for (int s = 0; s < 4; ++s) ov[s] = bf2f(u[s]) * iv[s] * g;
    *(f32x4*)(out + flat) = ov;
}

extern "C" void kernel_launch(void* const* d_in, const int* in_sizes, int n_in,
                              void* d_out, int out_size, void* d_ws, size_t ws_size,
                              hipStream_t stream) {
    (void)in_sizes; (void)n_in; (void)out_size; (void)ws_size;
    const float* x     = (const float*)d_in[0];
    const float* g1    = (const float*)d_in[1];
    const float* w_qkv = (const float*)d_in[2];
    const float* w_out = (const float*)d_in[3];
    const float* b_out = (const float*)d_in[4];
    const float* g2    = (const float*)d_in[5];
    float* out = (float*)d_out;

    char* ws = (char*)d_ws;
    const size_t MB = 1024 * 1024;
    // [0,64): xnt -> attnT.  [64,192): kv; qbuf/y reuse [64,128), qhatT at [128,192).
    unsigned short* xnt   = (unsigned short*)(ws);
    unsigned short* attnT = xnt;
    unsigned short* kv    = (unsigned short*)(ws + 64 * MB);
    unsigned short* qbuf  = kv;
    unsigned short* y     = kv;
    unsigned short* qhatT = (unsigned short*)(ws + 128 * MB);
    unsigned short* wqkvb = (unsigned short*)(ws + 192 * MB);            // 1.5 MiB
    unsigned short* woutb = (unsigned short*)(ws + 192 * MB + 1536 * 1024); // 0.5 MiB
    float* inv1 = (float*)(ws + 194 * MB);
    float* inv2 = (float*)(ws + 194 * MB + 256 * 1024);
    float* kst  = (float*)(ws + 194 * MB + 512 * 1024);
    float* ctxT = (float*)(ws + 195 * MB);                               // 2 MiB
    float* ctxP = (float*)(ws + 197 * MB);                               // 16 MiB -> ends 213 MiB

    hipLaunchKernelGGL(convert_k, dim3(768), dim3(256), 0, stream, w_qkv, wqkvb, 196608);
    hipLaunchKernelGGL(convert_k, dim3(256), dim3(256), 0, stream, w_out, woutb, 65536);
    hipLaunchKernelGGL(inv_stats_x_k, dim3(256), dim3(256), 0, stream, x, inv1);
    hipLaunchKernelGGL(xnt_kernel, dim3(64, 8, 16), dim3(256), 0, stream, x, g1, inv1, xnt);
    // kv GEMM: rows 512..1535 of wqkvb, M=1024
    hipLaunchKernelGGL(gemm_bt_kernel, dim3(32, 8, 16), dim3(256), 0, stream,
                       wqkvb + 512 * GK, xnt, kv, (const float*)nullptr,
                       (long)NSP * CDIM, (long)1024 * NSP);
    hipLaunchKernelGGL(kstats_k, dim3(512, 16), dim3(256), 0, stream, kv, kst);
    hipLaunchKernelGGL(context_kernel, dim3(128, CTX_SLICES), dim3(256), 0, stream, kv, kst, ctxP);
    hipLaunchKernelGGL(ctxreduce_k, dim3(512), dim3(256), 0, stream, ctxP, ctxT);
    // q GEMM: rows 0..511, M=512 (overwrites dead k region)
    hipLaunchKernelGGL(gemm_bt_kernel, dim3(32, 4, 16), dim3(256), 0, stream,
                       wqkvb, xnt, qbuf, (const float*)nullptr,
                       (long)NSP * CDIM, (long)512 * NSP);
    hipLaunchKernelGGL(qhat_kernel, dim3(16, 8, 16), dim3(256), 0, stream, qbuf, qhatT);
    hipLaunchKernelGGL(attnout_kernel, dim3(128, 16), dim3(256), 0, stream, ctxT, qhatT, attnT);
    hipLaunchKernelGGL(gemm_bt_kernel, dim3(32, 4, 16), dim3(256), 0, stream,
                       woutb, attnT, y, b_out, (long)NSP * CDIM, (long)512 * NSP);
    hipLaunchKernelGGL(inv_stats_y_k, dim3(256), dim3(256), 0, stream, y, inv2);
    hipLaunchKernelGGL(final_kernel, dim3(32768), dim3(256), 0, stream, y, g2, inv2, out);
}

// Round 2
// 627.892 us; speedup vs baseline: 1.1924x; 1.1492x over previous
//
#include <hip/hip_runtime.h>

#define B_    16
#define CDIM  512
#define NSP   4096
#define GK    512
#define SQRTC 22.62741699796952f
#define CTX_SLICES 4

typedef __attribute__((ext_vector_type(4))) float f32x4;
typedef __attribute__((ext_vector_type(8))) short s16x8;
typedef __attribute__((ext_vector_type(4))) unsigned short u16x4;
typedef __attribute__((ext_vector_type(8))) unsigned short u16x8;

__device__ __forceinline__ float bf2f(unsigned short u) {
    union { unsigned int i; float f; } v; v.i = ((unsigned int)u) << 16; return v.f;
}
__device__ __forceinline__ unsigned short f2bf(float f) {
    union { float fl; unsigned int i; } v; v.fl = f;
    unsigned int r = v.i + 0x7FFFu + ((v.i >> 16) & 1u);
    return (unsigned short)(r >> 16);
}

// async global -> LDS, 16B per lane. LDS dest is wave-uniform base; HW adds lane*16.
// Global source address IS per-lane -> swizzled layouts via pre-swizzled source.
__device__ __forceinline__ void gload16(const unsigned short* g, unsigned short* l) {
    __builtin_amdgcn_global_load_lds(
        (const __attribute__((address_space(1))) unsigned int*)g,
        (__attribute__((address_space(3))) unsigned int*)l,
        16, 0, 0);
}

// ---------------- fp32 -> bf16 weight conversion
__global__ __launch_bounds__(256) void convert_k(const float* __restrict__ in,
                                                 unsigned short* __restrict__ out, int n4) {
    int i = blockIdx.x * 256 + threadIdx.x;
    if (i >= n4) return;
    f32x4 v = *(const f32x4*)(in + (long)i * 4);
    u16x4 o;
    #pragma unroll
    for (int s = 0; s < 4; ++s) o[s] = f2bf(v[s]);
    *(u16x4*)(out + (long)i * 4) = o;
}

// ---------------- inv[b,n] = sqrt(512)/max(||x[b,:,n]||,eps), x fp32 [b,c,n]
// cooperative: block = (64-n chunk, b); 16 row-groups sweep c, LDS tree reduce.
__global__ __launch_bounds__(256) void inv_stats_x_k(const float* __restrict__ x,
                                                     float* __restrict__ inv) {
    __shared__ float red[16 * 64];
    int n0 = blockIdx.x * 64, b = blockIdx.y, t = threadIdx.x;
    int rg = t >> 4, c4 = (t & 15) * 4;
    const float* xb = x + (long)b * CDIM * NSP + n0 + c4;
    f32x4 ss = {0.f, 0.f, 0.f, 0.f};
    for (int c = rg; c < CDIM; c += 16) {
        f32x4 v = *(const f32x4*)(xb + (long)c * NSP);
        ss += v * v;
    }
    *(f32x4*)(red + rg * 64 + c4) = ss;
    __syncthreads();
    if (t < 64) {
        float s = 0.f;
        #pragma unroll
        for (int r = 0; r < 16; ++r) s += red[r * 64 + t];
        inv[b * NSP + n0 + t] = SQRTC / fmaxf(sqrtf(s), 1e-12f);
    }
}

// ---------------- inv over internal bf16 y [b,c,n], cooperative version
__global__ __launch_bounds__(256) void inv_stats_y_k(const unsigned short* __restrict__ y,
                                                     float* __restrict__ inv) {
    __shared__ float red[32 * 64];
    int n0 = blockIdx.x * 64, b = blockIdx.y, t = threadIdx.x;
    int rg = t >> 3, c8 = (t & 7) * 8;
    const unsigned short* yb = y + (long)b * CDIM * NSP + n0 + c8;
    float ss[8] = {};
    for (int c = rg; c < CDIM; c += 32) {
        u16x8 v = *(const u16x8*)(yb + (long)c * NSP);
        #pragma unroll
        for (int e = 0; e < 8; ++e) { float f = bf2f(v[e]); ss[e] += f * f; }
    }
    #pragma unroll
    for (int e = 0; e < 8; ++e) red[rg * 64 + c8 + e] = ss[e];
    __syncthreads();
    if (t < 64) {
        float s = 0.f;
        #pragma unroll
        for (int r = 0; r < 32; ++r) s += red[r * 64 + t];
        inv[b * NSP + n0 + t] = SQRTC / fmaxf(sqrtf(s), 1e-12f);
    }
}

// ---------------- xn_t[b][n][c] = x[b][c][n]*inv1[b,n]*g1[c]  (fp32 in, bf16 out, transpose)
__global__ __launch_bounds__(256) void xnt_kernel(const float* __restrict__ x,
                                                  const float* __restrict__ g1,
                                                  const float* __restrict__ inv,
                                                  unsigned short* __restrict__ xnt) {
    alignas(16) __shared__ float tile[64 * 68];
    int n0 = blockIdx.x * 64, c0 = blockIdx.y * 64, b = blockIdx.z;
    int t = threadIdx.x;
    #pragma unroll
    for (int it = 0; it < 4; ++it) {
        int idx = it * 256 + t;
        int r = idx >> 4, c4 = (idx & 15) * 4;          // r = c-row, c4 = n-col
        f32x4 v = *(const f32x4*)(x + (long)(b * CDIM + c0 + r) * NSP + n0 + c4);
        *(f32x4*)(tile + r * 68 + c4) = v;
    }
    __syncthreads();
    #pragma unroll
    for (int it = 0; it < 4; ++it) {
        int idx = it * 256 + t;
        int nr = idx >> 4, cc = (idx & 15) * 4;         // nr = n-row, cc = c-col
        float s = inv[b * NSP + n0 + nr];
        u16x4 o;
        #pragma unroll
        for (int si = 0; si < 4; ++si)
            o[si] = f2bf(tile[(cc + si) * 68 + nr] * s * g1[c0 + cc + si]);
        *(u16x4*)(xnt + (long)(b * NSP + n0 + nr) * CDIM + c0 + cc) = o;
    }
}

// ---------------- MFMA GEMM: C[b][m][n] = A[m][:].Bt[b][n][:] (+bias fp32), bf16 in/out
// LDS: global_load_lds (linear dest) + XOR-swizzled source + swizzled ds_read.
// Swizzle: 16B-chunk q' = q ^ ((row>>1)&3) -> each 8-lane phase hits 8 distinct bank groups.
__global__ __launch_bounds__(256, 2) void gemm_bt_kernel(
        const unsigned short* __restrict__ A, const unsigned short* __restrict__ Bt,
        unsigned short* __restrict__ C, const float* __restrict__ bias,
        long bt_bstride, long c_bstride) {
    alignas(16) __shared__ unsigned short As[128 * 32];
    alignas(16) __shared__ unsigned short Bs[128 * 32];
    const int t = threadIdx.x, wave = t >> 6, lane = t & 63;
    const int l15 = lane & 15, quad = lane >> 4;
    const int wm = (wave >> 1) * 64, wn = (wave & 1) * 64;
    const int m0 = blockIdx.y * 128, n0 = blockIdx.x * 128, b = blockIdx.z;
    const unsigned short* Bb = Bt + (long)b * bt_bstride;
    unsigned short* Cb = C + (long)b * c_bstride;

    f32x4 acc[4][4] = {};
    for (int k0 = 0; k0 < GK; k0 += 32) {
        #pragma unroll
        for (int it = 0; it < 2; ++it) {
            int idx = it * 256 + t;                       // 0..511, one 16B chunk each
            int row = idx >> 2;
            int c8 = (((idx & 3) ^ ((idx >> 3) & 3)) * 8);   // inverse-swizzled source col
            int wbase = (it * 256 + (t & 192)) * 8;       // wave-uniform LDS base (shorts)
            gload16(A  + (long)(m0 + row) * GK + k0 + c8, As + wbase);
            gload16(Bb + (long)(n0 + row) * GK + k0 + c8, Bs + wbase);
        }
        __syncthreads();
        s16x8 af[4], bfr[4];
        #pragma unroll
        for (int i = 0; i < 4; ++i) {
            int row = wm + i * 16 + l15;
            af[i]  = *(const s16x8*)(As + row * 32 + ((quad ^ ((row >> 1) & 3)) * 8));
        }
        #pragma unroll
        for (int j = 0; j < 4; ++j) {
            int row = wn + j * 16 + l15;
            bfr[j] = *(const s16x8*)(Bs + row * 32 + ((quad ^ ((row >> 1) & 3)) * 8));
        }
        #pragma unroll
        for (int i = 0; i < 4; ++i)
            #pragma unroll
            for (int j = 0; j < 4; ++j)
                acc[i][j] = __builtin_amdgcn_mfma_f32_16x16x32_bf16(af[i], bfr[j], acc[i][j], 0, 0, 0);
        __syncthreads();
    }
    #pragma unroll
    for (int i = 0; i < 4; ++i)
        #pragma unroll
        for (int r = 0; r < 4; ++r) {
            int row = m0 + wm + i * 16 + quad * 4 + r;
            float bv = bias ? bias[row] : 0.0f;
            #pragma unroll
            for (int j = 0; j < 4; ++j) {
                int col = n0 + wn + j * 16 + l15;
                Cb[(long)row * NSP + col] = f2bf(acc[i][j][r] + bv);
            }
        }
}

// ---------------- k softmax stats per (b,row): max, 1/sum(exp)
__global__ __launch_bounds__(256) void kstats_k(const unsigned short* __restrict__ kv,
                                                float* __restrict__ kst) {
    __shared__ float red[8];
    int row = blockIdx.x, b = blockIdx.y, t = threadIdx.x;
    int wave = t >> 6, lane = t & 63;
    const unsigned short* base = kv + ((long)b * 1024 + row) * NSP;
    float v[16];
    u16x8 a0 = *(const u16x8*)(base + t * 16);
    u16x8 a1 = *(const u16x8*)(base + t * 16 + 8);
    #pragma unroll
    for (int e = 0; e < 8; ++e) { v[e] = bf2f(a0[e]); v[8 + e] = bf2f(a1[e]); }
    float mx = v[0];
    #pragma unroll
    for (int e = 1; e < 16; ++e) mx = fmaxf(mx, v[e]);
    #pragma unroll
    for (int off = 32; off; off >>= 1) mx = fmaxf(mx, __shfl_xor(mx, off));
    if (lane == 0) red[wave] = mx;
    __syncthreads();
    mx = fmaxf(fmaxf(red[0], red[1]), fmaxf(red[2], red[3]));
    float sm = 0.f;
    #pragma unroll
    for (int e = 0; e < 16; ++e) sm += __expf(v[e] - mx);
    #pragma unroll
    for (int off = 32; off; off >>= 1) sm += __shfl_xor(sm, off);
    if (lane == 0) red[4 + wave] = sm;
    __syncthreads();
    if (t == 0) {
        float s = red[4] + red[5] + red[6] + red[7];
        kst[((long)b * 512 + row) * 2]     = mx;
        kst[((long)b * 512 + row) * 2 + 1] = 1.f / s;
    }
}

// ---------------- ctxP[slice][bh][e*64+d] = sum_{n in slice} khat[d,n]*v[e,n]
// LDS-staged (coalesced 512B-row gload_lds, swizzled), exp in-place in LDS,
// wave owns e-quarter (j = wave) -> NO cross-wave reduce, plain stores.
__global__ __launch_bounds__(256, 2) void context_kernel(const unsigned short* __restrict__ kv,
                                                         const float* __restrict__ kst,
                                                         float* __restrict__ ctxP) {
    alignas(16) __shared__ unsigned short Ks[64 * 256];   // 32 KB, swizzled
    alignas(16) __shared__ unsigned short Vs[64 * 256];   // 32 KB, swizzled
    int bh = blockIdx.x, b = bh >> 3, h = bh & 7;
    int t = threadIdx.x, wave = t >> 6, lane = t & 63, l15 = lane & 15, quad = lane >> 4;
    const unsigned short* kp = kv + ((long)b * 1024 + h * 64) * NSP;
    const unsigned short* vp = kv + ((long)b * 1024 + 512 + h * 64) * NSP;
    // stats for the 8 d-rows this thread exp-converts (row = u*8 + (t>>5))
    float mxu[8], rsu[8];
    #pragma unroll
    for (int u = 0; u < 8; ++u) {
        int row = u * 8 + (t >> 5);
        mxu[u] = kst[((long)b * 512 + h * 64 + row) * 2];
        rsu[u] = kst[((long)b * 512 + h * 64 + row) * 2 + 1];
    }
    f32x4 acc[4] = {};
    for (int tile = 0; tile < 4; ++tile) {
        int n0 = blockIdx.y * 1024 + tile * 256;
        // ---- stage K and V (row = 512B contiguous; source col pre-swizzled)
        #pragma unroll
        for (int is = 0; is < 8; ++is) {
            int cidx = (wave * 8 + is) * 64 + lane;       // 16B-chunk index 0..2047
            int row = cidx >> 5, cq = cidx & 31;
            int sc = (cq ^ (row & 7)) * 8;                // shorts
            gload16(kp + (long)row * NSP + n0 + sc, Ks + (wave * 8 + is) * 512);
            gload16(vp + (long)row * NSP + n0 + sc, Vs + (wave * 8 + is) * 512);
        }
        __syncthreads();
        // ---- in-place exp on K tile (chunk = u*256 + t -> conflict-free, row = u*8 + t>>5)
        #pragma unroll
        for (int u = 0; u < 8; ++u) {
            unsigned short* p = Ks + ((u * 256 + t) * 8);
            u16x8 v = *(const u16x8*)p;
            u16x8 o;
            #pragma unroll
            for (int e = 0; e < 8; ++e)
                o[e] = f2bf(__expf(bf2f(v[e]) - mxu[u]) * rsu[u]);
            *(u16x8*)p = o;
        }
        __syncthreads();
        // ---- MFMA: all waves read full K tile; wave reads its own V rows (j = wave)
        #pragma unroll
        for (int ks = 0; ks < 8; ++ks) {
            s16x8 af[4], bfr;
            #pragma unroll
            for (int i = 0; i < 4; ++i) {
                int row = i * 16 + l15;
                af[i] = *(const s16x8*)(Ks + row * 256 + (((ks * 4 + quad) ^ (row & 7)) * 8));
            }
            {
                int row = wave * 16 + l15;
                bfr = *(const s16x8*)(Vs + row * 256 + (((ks * 4 + quad) ^ (row & 7)) * 8));
            }
            #pragma unroll
            for (int i = 0; i < 4; ++i)
                acc[i] = __builtin_amdgcn_mfma_f32_16x16x32_bf16(af[i], bfr, acc[i], 0, 0, 0);
        }
        __syncthreads();
    }
    float* cp = ctxP + ((long)blockIdx.y * 128 + bh) * 4096;
    #pragma unroll
    for (int i = 0; i < 4; ++i)
        *(f32x4*)(cp + (wave * 16 + l15) * 64 + i * 16 + quad * 4) = acc[i];
}

// ---------------- ctxT = sum over slices of ctxP
__global__ __launch_bounds__(256) void ctxreduce_k(const float* __restrict__ ctxP,
                                                   float* __restrict__ ctxT) {
    long i = ((long)blockIdx.x * 256 + threadIdx.x) * 4;
    f32x4 s = *(const f32x4*)(ctxP + i);
    #pragma unroll
    for (int sl = 1; sl < CTX_SLICES; ++sl) {
        f32x4 v = *(const f32x4*)(ctxP + (long)sl * 128 * 4096 + i);
        s += v;
    }
    *(f32x4*)(ctxT + i) = s;
}

// ---------------- qhatT[bh][n][d] = softmax_d(q)[d,n]*0.125  (bf16, d contiguous)
__global__ __launch_bounds__(256) void qhat_kernel(const unsigned short* __restrict__ qbuf,
                                                   unsigned short* __restrict__ qhatT) {
    alignas(16) __shared__ unsigned short tile[64 * 256];
    int n0 = blockIdx.x * 256, h = blockIdx.y, b = blockIdx.z, t = threadIdx.x;
    const unsigned short* qp = qbuf + ((long)b * 512 + h * 64) * NSP;
    #pragma unroll
    for (int it = 0; it < 16; ++it) {
        int idx = it * 256 + t;
        int d = idx >> 6, c4 = (idx & 63) * 4;
        *(u16x4*)(tile + d * 256 + c4) = *(const u16x4*)(qp + (long)d * NSP + n0 + c4);
    }
    __syncthreads();
    float mx = -3.4e38f;
    for (int d = 0; d < 64; ++d) mx = fmaxf(mx, bf2f(tile[d * 256 + t]));
    float sum = 0.f;
    for (int d = 0; d < 64; ++d) sum += __expf(bf2f(tile[d * 256 + t]) - mx);
    float rsc = 0.125f / sum;
    unsigned short* op = qhatT + ((long)(b * 8 + h) * NSP + n0 + t) * 64;
    #pragma unroll
    for (int d4 = 0; d4 < 16; ++d4) {
        u16x4 o;
        #pragma unroll
        for (int si = 0; si < 4; ++si)
            o[si] = f2bf(__expf(bf2f(tile[(d4 * 4 + si) * 256 + t]) - mx) * rsc);
        *(u16x4*)(op + d4 * 4) = o;
    }
}

// ---------------- attnT[b][n][h*64+e] = sum_d ctxT[e][d]*qhatT[n][d]   (MFMA)
__global__ __launch_bounds__(256) void attnout_kernel(const float* __restrict__ ctxT,
                                                      const unsigned short* __restrict__ qhatT,
                                                      unsigned short* __restrict__ attnT) {
    int bh = blockIdx.x, b = bh >> 3, h = bh & 7;
    int t = threadIdx.x, wave = t >> 6, lane = t & 63, l15 = lane & 15, quad = lane >> 4;
    int n0 = blockIdx.y * 256 + wave * 64;
    const float* cb = ctxT + (long)bh * 4096;
    s16x8 af[2][4];
    #pragma unroll
    for (int ks = 0; ks < 2; ++ks)
        #pragma unroll
        for (int i = 0; i < 4; ++i) {
            const float* src = cb + (i * 16 + l15) * 64 + ks * 32 + quad * 8;
            s16x8 a;
            #pragma unroll
            for (int e = 0; e < 8; ++e) a[e] = (short)f2bf(src[e]);
            af[ks][i] = a;
        }
    f32x4 acc[4][4] = {};
    const unsigned short* qb = qhatT + (long)bh * NSP * 64;
    #pragma unroll
    for (int ks = 0; ks < 2; ++ks) {
        s16x8 bfr[4];
        #pragma unroll
        for (int j = 0; j < 4; ++j)
            bfr[j] = *(const s16x8*)(qb + (long)(n0 + j * 16 + l15) * 64 + ks * 32 + quad * 8);
        #pragma unroll
        for (int i = 0; i < 4; ++i)
            #pragma unroll
            for (int j = 0; j < 4; ++j)
                acc[i][j] = __builtin_amdgcn_mfma_f32_16x16x32_bf16(af[ks][i], bfr[j], acc[i][j], 0, 0, 0);
    }
    #pragma unroll
    for (int i = 0; i < 4; ++i)
        #pragma unroll
        for (int j = 0; j < 4; ++j) {
            int n = n0 + j * 16 + l15;
            u16x4 o;
            #pragma unroll
            for (int r = 0; r < 4; ++r) o[r] = f2bf(acc[i][j][r]);
            *(u16x4*)(attnT + ((long)b * NSP + n) * CDIM + h * 64 + i * 16 + quad * 4) = o;
        }
}

// ---------------- out fp32 = y_bf16 * inv2[b,n] * g2[c]
__global__ __launch_bounds__(256) void final_kernel(const unsigned short* __restrict__ y,
                                                    const float* __restrict__ g2,
                                                    const float* __restrict__ inv2,
                                                    float* __restrict__ out) {
    long flat = ((long)blockIdx.x * 256 + threadIdx.x) * 4;
    int b = (int)(flat >> 21);
    int rem = (int)(flat & ((1 << 21) - 1));
    int c = rem >> 12, n = rem & 4095;
    u16x4 u = *(const u16x4*)(y + flat);
    f32x4 iv = *(const f32x4*)(inv2 + b * NSP + n);
    float g = g2[c];
    f32x4 ov;
    #pragma unroll
    for (int s = 0; s < 4; ++s) ov[s] = bf2f(u[s]) * iv[s] * g;
    *(f32x4*)(out + flat) = ov;
}

extern "C" void kernel_launch(void* const* d_in, const int* in_sizes, int n_in,
                              void* d_out, int out_size, void* d_ws, size_t ws_size,
                              hipStream_t stream) {
    (void)in_sizes; (void)n_in; (void)out_size; (void)ws_size;
    const float* x     = (const float*)d_in[0];
    const float* g1    = (const float*)d_in[1];
    const float* w_qkv = (const float*)d_in[2];
    const float* w_out = (const float*)d_in[3];
    const float* b_out = (const float*)d_in[4];
    const float* g2    = (const float*)d_in[5];
    float* out = (float*)d_out;

    char* ws = (char*)d_ws;
    const size_t MB = 1024 * 1024;
    // [0,64): xnt -> attnT.  [64,192): kv; qbuf/y reuse [64,128), qhatT at [128,192).
    unsigned short* xnt   = (unsigned short*)(ws);
    unsigned short* attnT = xnt;
    unsigned short* kv    = (unsigned short*)(ws + 64 * MB);
    unsigned short* qbuf  = kv;
    unsigned short* y     = kv;
    unsigned short* qhatT = (unsigned short*)(ws + 128 * MB);
    unsigned short* wqkvb = (unsigned short*)(ws + 192 * MB);            // 1.5 MiB
    unsigned short* woutb = (unsigned short*)(ws + 192 * MB + 1536 * 1024); // 0.5 MiB
    float* inv1 = (float*)(ws + 194 * MB);
    float* inv2 = (float*)(ws + 194 * MB + 256 * 1024);
    float* kst  = (float*)(ws + 194 * MB + 512 * 1024);
    float* ctxT = (float*)(ws + 195 * MB);                               // 2 MiB
    float* ctxP = (float*)(ws + 197 * MB);                               // 8 MiB -> ends 205 MiB

    hipLaunchKernelGGL(convert_k, dim3(768), dim3(256), 0, stream, w_qkv, wqkvb, 196608);
    hipLaunchKernelGGL(convert_k, dim3(256), dim3(256), 0, stream, w_out, woutb, 65536);
    hipLaunchKernelGGL(inv_stats_x_k, dim3(64, 16), dim3(256), 0, stream, x, inv1);
    hipLaunchKernelGGL(xnt_kernel, dim3(64, 8, 16), dim3(256), 0, stream, x, g1, inv1, xnt);
    // kv GEMM: rows 512..1535 of wqkvb, M=1024
    hipLaunchKernelGGL(gemm_bt_kernel, dim3(32, 8, 16), dim3(256), 0, stream,
                       wqkvb + 512 * GK, xnt, kv, (const float*)nullptr,
                       (long)NSP * CDIM, (long)1024 * NSP);
    hipLaunchKernelGGL(kstats_k, dim3(512, 16), dim3(256), 0, stream, kv, kst);
    hipLaunchKernelGGL(context_kernel, dim3(128, CTX_SLICES), dim3(256), 0, stream, kv, kst, ctxP);
    hipLaunchKernelGGL(ctxreduce_k, dim3(512), dim3(256), 0, stream, ctxP, ctxT);
    // q GEMM: rows 0..511, M=512 (overwrites dead k region)
    hipLaunchKernelGGL(gemm_bt_kernel, dim3(32, 4, 16), dim3(256), 0, stream,
                       wqkvb, xnt, qbuf, (const float*)nullptr,
                       (long)NSP * CDIM, (long)512 * NSP);
    hipLaunchKernelGGL(qhat_kernel, dim3(16, 8, 16), dim3(256), 0, stream, qbuf, qhatT);
    hipLaunchKernelGGL(attnout_kernel, dim3(128, 16), dim3(256), 0, stream, ctxT, qhatT, attnT);
    hipLaunchKernelGGL(gemm_bt_kernel, dim3(32, 4, 16), dim3(256), 0, stream,
                       woutb, attnT, y, b_out, (long)NSP * CDIM, (long)512 * NSP);
    hipLaunchKernelGGL(inv_stats_y_k, dim3(64, 16), dim3(256), 0, stream, y, inv2);
    hipLaunchKernelGGL(final_kernel, dim3(32768), dim3(256), 0, stream, y, g2, inv2, out);
}

// Round 3
// 594.244 us; speedup vs baseline: 1.2599x; 1.0566x over previous
//
#include <hip/hip_runtime.h>

#define B_    16
#define CDIM  512
#define NSP   4096
#define GK    512
#define SQRTC 22.62741699796952f
#define CTX_SLICES 4

typedef __attribute__((ext_vector_type(4))) float f32x4;
typedef __attribute__((ext_vector_type(8))) short s16x8;
typedef __attribute__((ext_vector_type(4))) unsigned short u16x4;
typedef __attribute__((ext_vector_type(8))) unsigned short u16x8;

__device__ __forceinline__ float bf2f(unsigned short u) {
    union { unsigned int i; float f; } v; v.i = ((unsigned int)u) << 16; return v.f;
}
__device__ __forceinline__ unsigned short f2bf(float f) {
    union { float fl; unsigned int i; } v; v.fl = f;
    unsigned int r = v.i + 0x7FFFu + ((v.i >> 16) & 1u);
    return (unsigned short)(r >> 16);
}

// async global -> LDS, 16B per lane. LDS dest is wave-uniform base; HW adds lane*16.
// Global source address IS per-lane -> swizzled layouts via pre-swizzled source.
__device__ __forceinline__ void gload16(const unsigned short* g, unsigned short* l) {
    __builtin_amdgcn_global_load_lds(
        (const __attribute__((address_space(1))) unsigned int*)g,
        (__attribute__((address_space(3))) unsigned int*)l,
        16, 0, 0);
}

// ---------------- fp32 -> bf16 weight conversion
__global__ __launch_bounds__(256) void convert_k(const float* __restrict__ in,
                                                 unsigned short* __restrict__ out, int n4) {
    int i = blockIdx.x * 256 + threadIdx.x;
    if (i >= n4) return;
    f32x4 v = *(const f32x4*)(in + (long)i * 4);
    u16x4 o;
    #pragma unroll
    for (int s = 0; s < 4; ++s) o[s] = f2bf(v[s]);
    *(u16x4*)(out + (long)i * 4) = o;
}

// ---------------- inv[b,n] = sqrt(512)/max(||x[b,:,n]||,eps), x fp32 [b,c,n]
__global__ __launch_bounds__(256) void inv_stats_x_k(const float* __restrict__ x,
                                                     float* __restrict__ inv) {
    __shared__ float red[16 * 64];
    int n0 = blockIdx.x * 64, b = blockIdx.y, t = threadIdx.x;
    int rg = t >> 4, c4 = (t & 15) * 4;
    const float* xb = x + (long)b * CDIM * NSP + n0 + c4;
    f32x4 ss = {0.f, 0.f, 0.f, 0.f};
    for (int c = rg; c < CDIM; c += 16) {
        f32x4 v = *(const f32x4*)(xb + (long)c * NSP);
        ss += v * v;
    }
    *(f32x4*)(red + rg * 64 + c4) = ss;
    __syncthreads();
    if (t < 64) {
        float s = 0.f;
        #pragma unroll
        for (int r = 0; r < 16; ++r) s += red[r * 64 + t];
        inv[b * NSP + n0 + t] = SQRTC / fmaxf(sqrtf(s), 1e-12f);
    }
}

// ---------------- xn_t[b][n][c] = x[b][c][n]*inv1[b,n]*g1[c]  (fp32 in, bf16 out, transpose)
__global__ __launch_bounds__(256) void xnt_kernel(const float* __restrict__ x,
                                                  const float* __restrict__ g1,
                                                  const float* __restrict__ inv,
                                                  unsigned short* __restrict__ xnt) {
    alignas(16) __shared__ float tile[64 * 68];
    int n0 = blockIdx.x * 64, c0 = blockIdx.y * 64, b = blockIdx.z;
    int t = threadIdx.x;
    #pragma unroll
    for (int it = 0; it < 4; ++it) {
        int idx = it * 256 + t;
        int r = idx >> 4, c4 = (idx & 15) * 4;          // r = c-row, c4 = n-col
        f32x4 v = *(const f32x4*)(x + (long)(b * CDIM + c0 + r) * NSP + n0 + c4);
        *(f32x4*)(tile + r * 68 + c4) = v;
    }
    __syncthreads();
    #pragma unroll
    for (int it = 0; it < 4; ++it) {
        int idx = it * 256 + t;
        int nr = idx >> 4, cc = (idx & 15) * 4;         // nr = n-row, cc = c-col
        float s = inv[b * NSP + n0 + nr];
        u16x4 o;
        #pragma unroll
        for (int si = 0; si < 4; ++si)
            o[si] = f2bf(tile[(cc + si) * 68 + nr] * s * g1[c0 + cc + si]);
        *(u16x4*)(xnt + (long)(b * NSP + n0 + nr) * CDIM + c0 + cc) = o;
    }
}

// ---------------- MFMA GEMM: C[b][m][n] = A[m][:].Bt[b][n][:] (+bias), bf16 in/out.
// Optional ssq: per-column sum of squares of final (bias-added) values, atomically
// accumulated into ssq[b*NSP+col] (fuses the downstream column-norm pass).
__global__ __launch_bounds__(256, 2) void gemm_bt_kernel(
        const unsigned short* __restrict__ A, const unsigned short* __restrict__ Bt,
        unsigned short* __restrict__ C, const float* __restrict__ bias,
        float* __restrict__ ssq,
        long bt_bstride, long c_bstride) {
    alignas(16) __shared__ unsigned short As[128 * 32];
    alignas(16) __shared__ unsigned short Bs[128 * 32];
    const int t = threadIdx.x, wave = t >> 6, lane = t & 63;
    const int l15 = lane & 15, quad = lane >> 4;
    const int wm = (wave >> 1) * 64, wn = (wave & 1) * 64;
    const int m0 = blockIdx.y * 128, n0 = blockIdx.x * 128, b = blockIdx.z;
    const unsigned short* Bb = Bt + (long)b * bt_bstride;
    unsigned short* Cb = C + (long)b * c_bstride;

    f32x4 acc[4][4] = {};
    for (int k0 = 0; k0 < GK; k0 += 32) {
        #pragma unroll
        for (int it = 0; it < 2; ++it) {
            int idx = it * 256 + t;                       // 0..511, one 16B chunk each
            int row = idx >> 2;
            int c8 = (((idx & 3) ^ ((idx >> 3) & 3)) * 8);   // inverse-swizzled source col
            int wbase = (it * 256 + (t & 192)) * 8;       // wave-uniform LDS base (shorts)
            gload16(A  + (long)(m0 + row) * GK + k0 + c8, As + wbase);
            gload16(Bb + (long)(n0 + row) * GK + k0 + c8, Bs + wbase);
        }
        __syncthreads();
        s16x8 af[4], bfr[4];
        #pragma unroll
        for (int i = 0; i < 4; ++i) {
            int row = wm + i * 16 + l15;
            af[i]  = *(const s16x8*)(As + row * 32 + ((quad ^ ((row >> 1) & 3)) * 8));
        }
        #pragma unroll
        for (int j = 0; j < 4; ++j) {
            int row = wn + j * 16 + l15;
            bfr[j] = *(const s16x8*)(Bs + row * 32 + ((quad ^ ((row >> 1) & 3)) * 8));
        }
        #pragma unroll
        for (int i = 0; i < 4; ++i)
            #pragma unroll
            for (int j = 0; j < 4; ++j)
                acc[i][j] = __builtin_amdgcn_mfma_f32_16x16x32_bf16(af[i], bfr[j], acc[i][j], 0, 0, 0);
        __syncthreads();
    }
    if (bias) {
        #pragma unroll
        for (int i = 0; i < 4; ++i)
            #pragma unroll
            for (int r = 0; r < 4; ++r) {
                float bv = bias[m0 + wm + i * 16 + quad * 4 + r];
                #pragma unroll
                for (int j = 0; j < 4; ++j) acc[i][j][r] += bv;
            }
    }
    #pragma unroll
    for (int i = 0; i < 4; ++i)
        #pragma unroll
        for (int r = 0; r < 4; ++r) {
            int row = m0 + wm + i * 16 + quad * 4 + r;
            #pragma unroll
            for (int j = 0; j < 4; ++j) {
                int col = n0 + wn + j * 16 + l15;
                Cb[(long)row * NSP + col] = f2bf(acc[i][j][r]);
            }
        }
    if (ssq) {
        float* sb = ssq + (long)b * NSP;
        #pragma unroll
        for (int j = 0; j < 4; ++j) {
            float p = 0.f;
            #pragma unroll
            for (int i = 0; i < 4; ++i)
                #pragma unroll
                for (int r = 0; r < 4; ++r) p += acc[i][j][r] * acc[i][j][r];
            p += __shfl_xor(p, 16);
            p += __shfl_xor(p, 32);
            if (quad == 0) atomicAdd(sb + n0 + wn + j * 16 + l15, p);
        }
    }
}

// ---------------- q GEMM with fused softmax-over-d epilogue -> qhatT[bh][n][d]*0.125
// Each wave's acc covers one full head's 64 d-rows for 64 columns, so the softmax
// is 16 regs + shfl_xor(16/32) across quads. No qbuf, no separate qhat pass.
__global__ __launch_bounds__(256, 2) void gemm_q_softmax_kernel(
        const unsigned short* __restrict__ A, const unsigned short* __restrict__ Bt,
        unsigned short* __restrict__ qhatT, long bt_bstride) {
    alignas(16) __shared__ unsigned short As[128 * 32];
    alignas(16) __shared__ unsigned short Bs[128 * 32];
    const int t = threadIdx.x, wave = t >> 6, lane = t & 63;
    const int l15 = lane & 15, quad = lane >> 4;
    const int wm = (wave >> 1) * 64, wn = (wave & 1) * 64;
    const int m0 = blockIdx.y * 128, n0 = blockIdx.x * 128, b = blockIdx.z;
    const unsigned short* Bb = Bt + (long)b * bt_bstride;

    f32x4 acc[4][4] = {};
    for (int k0 = 0; k0 < GK; k0 += 32) {
        #pragma unroll
        for (int it = 0; it < 2; ++it) {
            int idx = it * 256 + t;
            int row = idx >> 2;
            int c8 = (((idx & 3) ^ ((idx >> 3) & 3)) * 8);
            int wbase = (it * 256 + (t & 192)) * 8;
            gload16(A  + (long)(m0 + row) * GK + k0 + c8, As + wbase);
            gload16(Bb + (long)(n0 + row) * GK + k0 + c8, Bs + wbase);
        }
        __syncthreads();
        s16x8 af[4], bfr[4];
        #pragma unroll
        for (int i = 0; i < 4; ++i) {
            int row = wm + i * 16 + l15;
            af[i]  = *(const s16x8*)(As + row * 32 + ((quad ^ ((row >> 1) & 3)) * 8));
        }
        #pragma unroll
        for (int j = 0; j < 4; ++j) {
            int row = wn + j * 16 + l15;
            bfr[j] = *(const s16x8*)(Bs + row * 32 + ((quad ^ ((row >> 1) & 3)) * 8));
        }
        #pragma unroll
        for (int i = 0; i < 4; ++i)
            #pragma unroll
            for (int j = 0; j < 4; ++j)
                acc[i][j] = __builtin_amdgcn_mfma_f32_16x16x32_bf16(af[i], bfr[j], acc[i][j], 0, 0, 0);
        __syncthreads();
    }
    // softmax over d (the wave's 64 rows = head h), then *0.125, write d-contiguous
    const int h = (m0 + wm) >> 6;
    unsigned short* qb = qhatT + (long)(b * 8 + h) * NSP * 64;
    #pragma unroll
    for (int j = 0; j < 4; ++j) {
        float mx = -3.4e38f;
        #pragma unroll
        for (int i = 0; i < 4; ++i)
            #pragma unroll
            for (int r = 0; r < 4; ++r) mx = fmaxf(mx, acc[i][j][r]);
        mx = fmaxf(mx, __shfl_xor(mx, 16));
        mx = fmaxf(mx, __shfl_xor(mx, 32));
        float sm = 0.f;
        #pragma unroll
        for (int i = 0; i < 4; ++i)
            #pragma unroll
            for (int r = 0; r < 4; ++r) {
                float p = __expf(acc[i][j][r] - mx);
                acc[i][j][r] = p;
                sm += p;
            }
        sm += __shfl_xor(sm, 16);
        sm += __shfl_xor(sm, 32);
        float rsc = 0.125f / sm;
        int col = n0 + wn + j * 16 + l15;
        unsigned short* op = qb + (long)col * 64 + quad * 4;
        #pragma unroll
        for (int i = 0; i < 4; ++i) {
            u16x4 o;
            #pragma unroll
            for (int r = 0; r < 4; ++r) o[r] = f2bf(acc[i][j][r] * rsc);
            *(u16x4*)(op + i * 16) = o;
        }
    }
}

// ---------------- k softmax stats per (b,row): max, 1/sum(exp)
__global__ __launch_bounds__(256) void kstats_k(const unsigned short* __restrict__ kv,
                                                float* __restrict__ kst) {
    __shared__ float red[8];
    int row = blockIdx.x, b = blockIdx.y, t = threadIdx.x;
    int wave = t >> 6, lane = t & 63;
    const unsigned short* base = kv + ((long)b * 1024 + row) * NSP;
    float v[16];
    u16x8 a0 = *(const u16x8*)(base + t * 16);
    u16x8 a1 = *(const u16x8*)(base + t * 16 + 8);
    #pragma unroll
    for (int e = 0; e < 8; ++e) { v[e] = bf2f(a0[e]); v[8 + e] = bf2f(a1[e]); }
    float mx = v[0];
    #pragma unroll
    for (int e = 1; e < 16; ++e) mx = fmaxf(mx, v[e]);
    #pragma unroll
    for (int off = 32; off; off >>= 1) mx = fmaxf(mx, __shfl_xor(mx, off));
    if (lane == 0) red[wave] = mx;
    __syncthreads();
    mx = fmaxf(fmaxf(red[0], red[1]), fmaxf(red[2], red[3]));
    float sm = 0.f;
    #pragma unroll
    for (int e = 0; e < 16; ++e) sm += __expf(v[e] - mx);
    #pragma unroll
    for (int off = 32; off; off >>= 1) sm += __shfl_xor(sm, off);
    if (lane == 0) red[4 + wave] = sm;
    __syncthreads();
    if (t == 0) {
        float s = red[4] + red[5] + red[6] + red[7];
        kst[((long)b * 512 + row) * 2]     = mx;
        kst[((long)b * 512 + row) * 2 + 1] = 1.f / s;
    }
}

// ---------------- ctxP[slice][bh][e*64+d] = sum_{n in slice} khat[d,n]*v[e,n]
__global__ __launch_bounds__(256, 2) void context_kernel(const unsigned short* __restrict__ kv,
                                                         const float* __restrict__ kst,
                                                         float* __restrict__ ctxP) {
    alignas(16) __shared__ unsigned short Ks[64 * 256];   // 32 KB, swizzled
    alignas(16) __shared__ unsigned short Vs[64 * 256];   // 32 KB, swizzled
    int bh = blockIdx.x, b = bh >> 3, h = bh & 7;
    int t = threadIdx.x, wave = t >> 6, lane = t & 63, l15 = lane & 15, quad = lane >> 4;
    const unsigned short* kp = kv + ((long)b * 1024 + h * 64) * NSP;
    const unsigned short* vp = kv + ((long)b * 1024 + 512 + h * 64) * NSP;
    float mxu[8], rsu[8];
    #pragma unroll
    for (int u = 0; u < 8; ++u) {
        int row = u * 8 + (t >> 5);
        mxu[u] = kst[((long)b * 512 + h * 64 + row) * 2];
        rsu[u] = kst[((long)b * 512 + h * 64 + row) * 2 + 1];
    }
    f32x4 acc[4] = {};
    for (int tile = 0; tile < 4; ++tile) {
        int n0 = blockIdx.y * 1024 + tile * 256;
        #pragma unroll
        for (int is = 0; is < 8; ++is) {
            int cidx = (wave * 8 + is) * 64 + lane;       // 16B-chunk index 0..2047
            int row = cidx >> 5, cq = cidx & 31;
            int sc = (cq ^ (row & 7)) * 8;                // shorts
            gload16(kp + (long)row * NSP + n0 + sc, Ks + (wave * 8 + is) * 512);
            gload16(vp + (long)row * NSP + n0 + sc, Vs + (wave * 8 + is) * 512);
        }
        __syncthreads();
        #pragma unroll
        for (int u = 0; u < 8; ++u) {
            unsigned short* p = Ks + ((u * 256 + t) * 8);
            u16x8 v = *(const u16x8*)p;
            u16x8 o;
            #pragma unroll
            for (int e = 0; e < 8; ++e)
                o[e] = f2bf(__expf(bf2f(v[e]) - mxu[u]) * rsu[u]);
            *(u16x8*)p = o;
        }
        __syncthreads();
        #pragma unroll
        for (int ks = 0; ks < 8; ++ks) {
            s16x8 af[4], bfr;
            #pragma unroll
            for (int i = 0; i < 4; ++i) {
                int row = i * 16 + l15;
                af[i] = *(const s16x8*)(Ks + row * 256 + (((ks * 4 + quad) ^ (row & 7)) * 8));
            }
            {
                int row = wave * 16 + l15;
                bfr = *(const s16x8*)(Vs + row * 256 + (((ks * 4 + quad) ^ (row & 7)) * 8));
            }
            #pragma unroll
            for (int i = 0; i < 4; ++i)
                acc[i] = __builtin_amdgcn_mfma_f32_16x16x32_bf16(af[i], bfr, acc[i], 0, 0, 0);
        }
        __syncthreads();
    }
    float* cp = ctxP + ((long)blockIdx.y * 128 + bh) * 4096;
    #pragma unroll
    for (int i = 0; i < 4; ++i)
        *(f32x4*)(cp + (wave * 16 + l15) * 64 + i * 16 + quad * 4) = acc[i];
}

// ---------------- ctxT = sum over slices of ctxP
__global__ __launch_bounds__(256) void ctxreduce_k(const float* __restrict__ ctxP,
                                                   float* __restrict__ ctxT) {
    long i = ((long)blockIdx.x * 256 + threadIdx.x) * 4;
    f32x4 s = *(const f32x4*)(ctxP + i);
    #pragma unroll
    for (int sl = 1; sl < CTX_SLICES; ++sl) {
        f32x4 v = *(const f32x4*)(ctxP + (long)sl * 128 * 4096 + i);
        s += v;
    }
    *(f32x4*)(ctxT + i) = s;
}

// ---------------- attnT[b][n][h*64+e] = sum_d ctxT[e][d]*qhatT[n][d]   (MFMA)
__global__ __launch_bounds__(256) void attnout_kernel(const float* __restrict__ ctxT,
                                                      const unsigned short* __restrict__ qhatT,
                                                      unsigned short* __restrict__ attnT) {
    int bh = blockIdx.x, b = bh >> 3, h = bh & 7;
    int t = threadIdx.x, wave = t >> 6, lane = t & 63, l15 = lane & 15, quad = lane >> 4;
    int n0 = blockIdx.y * 256 + wave * 64;
    const float* cb = ctxT + (long)bh * 4096;
    s16x8 af[2][4];
    #pragma unroll
    for (int ks = 0; ks < 2; ++ks)
        #pragma unroll
        for (int i = 0; i < 4; ++i) {
            const float* src = cb + (i * 16 + l15) * 64 + ks * 32 + quad * 8;
            s16x8 a;
            #pragma unroll
            for (int e = 0; e < 8; ++e) a[e] = (short)f2bf(src[e]);
            af[ks][i] = a;
        }
    f32x4 acc[4][4] = {};
    const unsigned short* qb = qhatT + (long)bh * NSP * 64;
    #pragma unroll
    for (int ks = 0; ks < 2; ++ks) {
        s16x8 bfr[4];
        #pragma unroll
        for (int j = 0; j < 4; ++j)
            bfr[j] = *(const s16x8*)(qb + (long)(n0 + j * 16 + l15) * 64 + ks * 32 + quad * 8);
        #pragma unroll
        for (int i = 0; i < 4; ++i)
            #pragma unroll
            for (int j = 0; j < 4; ++j)
                acc[i][j] = __builtin_amdgcn_mfma_f32_16x16x32_bf16(af[ks][i], bfr[j], acc[i][j], 0, 0, 0);
    }
    #pragma unroll
    for (int i = 0; i < 4; ++i)
        #pragma unroll
        for (int j = 0; j < 4; ++j) {
            int n = n0 + j * 16 + l15;
            u16x4 o;
            #pragma unroll
            for (int r = 0; r < 4; ++r) o[r] = f2bf(acc[i][j][r]);
            *(u16x4*)(attnT + ((long)b * NSP + n) * CDIM + h * 64 + i * 16 + quad * 4) = o;
        }
}

// ---------------- out fp32 = y_bf16 * (SQRTC*rsqrt(ssq[b,n])) * g2[c]
__global__ __launch_bounds__(256) void final_kernel(const unsigned short* __restrict__ y,
                                                    const float* __restrict__ g2,
                                                    const float* __restrict__ ssq,
                                                    float* __restrict__ out) {
    long flat = ((long)blockIdx.x * 256 + threadIdx.x) * 4;
    int b = (int)(flat >> 21);
    int rem = (int)(flat & ((1 << 21) - 1));
    int c = rem >> 12, n = rem & 4095;
    u16x4 u = *(const u16x4*)(y + flat);
    f32x4 sq = *(const f32x4*)(ssq + b * NSP + n);
    float g = g2[c];
    f32x4 ov;
    #pragma unroll
    for (int s = 0; s < 4; ++s)
        ov[s] = bf2f(u[s]) * (SQRTC * rsqrtf(fmaxf(sq[s], 1e-24f))) * g;
    *(f32x4*)(out + flat) = ov;
}

extern "C" void kernel_launch(void* const* d_in, const int* in_sizes, int n_in,
                              void* d_out, int out_size, void* d_ws, size_t ws_size,
                              hipStream_t stream) {
    (void)in_sizes; (void)n_in; (void)out_size; (void)ws_size;
    const float* x     = (const float*)d_in[0];
    const float* g1    = (const float*)d_in[1];
    const float* w_qkv = (const float*)d_in[2];
    const float* w_out = (const float*)d_in[3];
    const float* b_out = (const float*)d_in[4];
    const float* g2    = (const float*)d_in[5];
    float* out = (float*)d_out;

    char* ws = (char*)d_ws;
    const size_t MB = 1024 * 1024;
    // [0,64): xnt -> attnT.  [64,192): kv; y reuses [64,128), qhatT at [128,192).
    unsigned short* xnt   = (unsigned short*)(ws);
    unsigned short* attnT = xnt;
    unsigned short* kv    = (unsigned short*)(ws + 64 * MB);
    unsigned short* y     = kv;
    unsigned short* qhatT = (unsigned short*)(ws + 128 * MB);
    unsigned short* wqkvb = (unsigned short*)(ws + 192 * MB);            // 1.5 MiB
    unsigned short* woutb = (unsigned short*)(ws + 192 * MB + 1536 * 1024); // 0.5 MiB
    float* inv1 = (float*)(ws + 194 * MB);
    float* ssq  = (float*)(ws + 194 * MB + 256 * 1024);                  // 256 KB
    float* kst  = (float*)(ws + 194 * MB + 512 * 1024);
    float* ctxT = (float*)(ws + 195 * MB);                               // 2 MiB
    float* ctxP = (float*)(ws + 197 * MB);                               // 8 MiB -> ends 205 MiB

    hipLaunchKernelGGL(convert_k, dim3(768), dim3(256), 0, stream, w_qkv, wqkvb, 196608);
    hipLaunchKernelGGL(convert_k, dim3(256), dim3(256), 0, stream, w_out, woutb, 65536);
    hipMemsetAsync(ssq, 0, (size_t)B_ * NSP * 4, stream);
    hipLaunchKernelGGL(inv_stats_x_k, dim3(64, 16), dim3(256), 0, stream, x, inv1);
    hipLaunchKernelGGL(xnt_kernel, dim3(64, 8, 16), dim3(256), 0, stream, x, g1, inv1, xnt);
    // kv GEMM: rows 512..1535 of wqkvb, M=1024
    hipLaunchKernelGGL(gemm_bt_kernel, dim3(32, 8, 16), dim3(256), 0, stream,
                       wqkvb + 512 * GK, xnt, kv, (const float*)nullptr, (float*)nullptr,
                       (long)NSP * CDIM, (long)1024 * NSP);
    hipLaunchKernelGGL(kstats_k, dim3(512, 16), dim3(256), 0, stream, kv, kst);
    hipLaunchKernelGGL(context_kernel, dim3(128, CTX_SLICES), dim3(256), 0, stream, kv, kst, ctxP);
    hipLaunchKernelGGL(ctxreduce_k, dim3(512), dim3(256), 0, stream, ctxP, ctxT);
    // q GEMM (rows 0..511) with fused softmax epilogue -> qhatT
    hipLaunchKernelGGL(gemm_q_softmax_kernel, dim3(32, 4, 16), dim3(256), 0, stream,
                       wqkvb, xnt, qhatT, (long)NSP * CDIM);
    hipLaunchKernelGGL(attnout_kernel, dim3(128, 16), dim3(256), 0, stream, ctxT, qhatT, attnT);
    // out GEMM with bias + fused column-ssq accumulation
    hipLaunchKernelGGL(gemm_bt_kernel, dim3(32, 4, 16), dim3(256), 0, stream,
                       woutb, attnT, y, b_out, ssq, (long)NSP * CDIM, (long)512 * NSP);
    hipLaunchKernelGGL(final_kernel, dim3(32768), dim3(256), 0, stream, y, g2, ssq, out);
}

// Round 4
// 571.311 us; speedup vs baseline: 1.3105x; 1.0401x over previous
//
#include <hip/hip_runtime.h>

#define B_    16
#define CDIM  512
#define NSP   4096
#define GK    512
#define SQRTC 22.62741699796952f
#define CTX_SLICES 4

typedef __attribute__((ext_vector_type(4))) float f32x4;
typedef __attribute__((ext_vector_type(8))) short s16x8;
typedef __attribute__((ext_vector_type(4))) unsigned short u16x4;
typedef __attribute__((ext_vector_type(8))) unsigned short u16x8;

__device__ __forceinline__ float bf2f(unsigned short u) {
    union { unsigned int i; float f; } v; v.i = ((unsigned int)u) << 16; return v.f;
}
__device__ __forceinline__ unsigned short f2bf(float f) {
    union { float fl; unsigned int i; } v; v.fl = f;
    unsigned int r = v.i + 0x7FFFu + ((v.i >> 16) & 1u);
    return (unsigned short)(r >> 16);
}

// async global -> LDS, 16B per lane. LDS dest is wave-uniform base; HW adds lane*16.
// Global source address IS per-lane -> swizzled layouts via pre-swizzled source.
__device__ __forceinline__ void gload16(const unsigned short* g, unsigned short* l) {
    __builtin_amdgcn_global_load_lds(
        (const __attribute__((address_space(1))) unsigned int*)g,
        (__attribute__((address_space(3))) unsigned int*)l,
        16, 0, 0);
}

// ---------------- fp32 -> bf16 weight conversion
__global__ __launch_bounds__(256) void convert_k(const float* __restrict__ in,
                                                 unsigned short* __restrict__ out, int n4) {
    int i = blockIdx.x * 256 + threadIdx.x;
    if (i >= n4) return;
    f32x4 v = *(const f32x4*)(in + (long)i * 4);
    u16x4 o;
    #pragma unroll
    for (int s = 0; s < 4; ++s) o[s] = f2bf(v[s]);
    *(u16x4*)(out + (long)i * 4) = o;
}

// ---------------- inv[b,n] = sqrt(512)/max(||x[b,:,n]||,eps), x fp32 [b,c,n]
__global__ __launch_bounds__(256) void inv_stats_x_k(const float* __restrict__ x,
                                                     float* __restrict__ inv) {
    __shared__ float red[16 * 64];
    int n0 = blockIdx.x * 64, b = blockIdx.y, t = threadIdx.x;
    int rg = t >> 4, c4 = (t & 15) * 4;
    const float* xb = x + (long)b * CDIM * NSP + n0 + c4;
    f32x4 ss = {0.f, 0.f, 0.f, 0.f};
    for (int c = rg; c < CDIM; c += 16) {
        f32x4 v = *(const f32x4*)(xb + (long)c * NSP);
        ss += v * v;
    }
    *(f32x4*)(red + rg * 64 + c4) = ss;
    __syncthreads();
    if (t < 64) {
        float s = 0.f;
        #pragma unroll
        for (int r = 0; r < 16; ++r) s += red[r * 64 + t];
        inv[b * NSP + n0 + t] = SQRTC / fmaxf(sqrtf(s), 1e-12f);
    }
}

// ---------------- xn_t[b][n][c] = x[b][c][n]*inv1[b,n]*g1[c]  (fp32 in, bf16 out, transpose)
__global__ __launch_bounds__(256) void xnt_kernel(const float* __restrict__ x,
                                                  const float* __restrict__ g1,
                                                  const float* __restrict__ inv,
                                                  unsigned short* __restrict__ xnt) {
    alignas(16) __shared__ float tile[64 * 68];
    int n0 = blockIdx.x * 64, c0 = blockIdx.y * 64, b = blockIdx.z;
    int t = threadIdx.x;
    #pragma unroll
    for (int it = 0; it < 4; ++it) {
        int idx = it * 256 + t;
        int r = idx >> 4, c4 = (idx & 15) * 4;          // r = c-row, c4 = n-col
        f32x4 v = *(const f32x4*)(x + (long)(b * CDIM + c0 + r) * NSP + n0 + c4);
        *(f32x4*)(tile + r * 68 + c4) = v;
    }
    __syncthreads();
    #pragma unroll
    for (int it = 0; it < 4; ++it) {
        int idx = it * 256 + t;
        int nr = idx >> 4, cc = (idx & 15) * 4;         // nr = n-row, cc = c-col
        float s = inv[b * NSP + n0 + nr];
        u16x4 o;
        #pragma unroll
        for (int si = 0; si < 4; ++si)
            o[si] = f2bf(tile[(cc + si) * 68 + nr] * s * g1[c0 + cc + si]);
        *(u16x4*)(xnt + (long)(b * NSP + n0 + nr) * CDIM + c0 + cc) = o;
    }
}

// ---------------- 256x256x64 double-buffered MFMA GEMM, 512 threads (8 waves, 2x4).
// C[b][m][n] = A[m][:].Bt[b][n][:].  EPI: 0 = plain bf16 C (kv GEMM),
// 1 = softmax-over-d epilogue -> qhatT (q GEMM), 2 = +bias +column-ssq (out GEMM).
// Structure: dist-1 prefetch (stage kt+1 during compute of kt), one raw s_barrier
// per K-tile, XOR-swizzled LDS (conflict-free ds_read_b128), setprio around MFMA.
template<int EPI>
__global__ __launch_bounds__(512, 2) void gemm256_kernel(
        const unsigned short* __restrict__ A, const unsigned short* __restrict__ Bt,
        unsigned short* __restrict__ C, const float* __restrict__ bias,
        float* __restrict__ ssq, long bt_bstride, long c_bstride) {
    alignas(16) __shared__ unsigned short As[2][256 * 64];   // 64 KB
    alignas(16) __shared__ unsigned short Bs[2][256 * 64];   // 64 KB
    const int t = threadIdx.x, lane = t & 63;
    const int l15 = lane & 15, quad = lane >> 4;
    const int wave = t >> 6, wr = wave >> 2, wc = wave & 3;   // 2 x 4 wave grid
    const int m0 = blockIdx.y * 256, n0 = blockIdx.x * 256, b = blockIdx.z;
    const unsigned short* Bb = Bt + (long)b * bt_bstride;

    // staging sources (kt-independent): 4 issues x (A,B); 16B chunk idx = is*512+t;
    // row = idx>>3, chunk-in-row cq = idx&7; source col chunk = cq ^ (row&7)  (inverse swizzle)
    const unsigned short* aSrc[4];
    const unsigned short* bSrc[4];
    int wb[4];
    #pragma unroll
    for (int is = 0; is < 4; ++is) {
        int idx = is * 512 + t;
        int row = idx >> 3, cq = idx & 7;
        int sc = (cq ^ (row & 7)) * 8;
        aSrc[is] = A  + (long)(m0 + row) * GK + sc;
        bSrc[is] = Bb + (long)(n0 + row) * GK + sc;
        wb[is] = (is * 512 + (t & 448)) * 8;     // wave-uniform LDS base (shorts)
    }

    f32x4 acc[8][4] = {};

    // prologue: stage kt=0 into buffer 0
    #pragma unroll
    for (int is = 0; is < 4; ++is) {
        gload16(aSrc[is], &As[0][0] + wb[is]);
        gload16(bSrc[is], &Bs[0][0] + wb[is]);
    }

    for (int kt = 0; kt < 8; ++kt) {
        // wait own staged loads of kt (issued one tile ago; latency hidden under compute)
        asm volatile("s_waitcnt vmcnt(0)" ::: "memory");
        __builtin_amdgcn_s_barrier();          // all waves: kt fully staged, kt-1 reads done
        asm volatile("" ::: "memory");
        if (kt < 7) {                          // issue kt+1 stage; overlaps compute of kt
            int kb = (kt + 1) * 64;
            unsigned short* dA = &As[(kt + 1) & 1][0];
            unsigned short* dB = &Bs[(kt + 1) & 1][0];
            #pragma unroll
            for (int is = 0; is < 4; ++is) {
                gload16(aSrc[is] + kb, dA + wb[is]);
                gload16(bSrc[is] + kb, dB + wb[is]);
            }
        }
        const unsigned short* Ab = &As[kt & 1][0];
        const unsigned short* Bp = &Bs[kt & 1][0];
        #pragma unroll
        for (int ks = 0; ks < 2; ++ks) {
            s16x8 af[8], bfv[4];
            #pragma unroll
            for (int i = 0; i < 8; ++i) {
                int row = wr * 128 + i * 16 + l15;
                af[i] = *(const s16x8*)(Ab + row * 64 + (((ks * 4 + quad) ^ (row & 7)) * 8));
            }
            #pragma unroll
            for (int j = 0; j < 4; ++j) {
                int row = wc * 64 + j * 16 + l15;
                bfv[j] = *(const s16x8*)(Bp + row * 64 + (((ks * 4 + quad) ^ (row & 7)) * 8));
            }
            __builtin_amdgcn_s_setprio(1);
            #pragma unroll
            for (int i = 0; i < 8; ++i)
                #pragma unroll
                for (int j = 0; j < 4; ++j)
                    acc[i][j] = __builtin_amdgcn_mfma_f32_16x16x32_bf16(af[i], bfv[j], acc[i][j], 0, 0, 0);
            __builtin_amdgcn_s_setprio(0);
        }
    }

    if (EPI == 0) {
        unsigned short* Cb = C + (long)b * c_bstride;
        #pragma unroll
        for (int i = 0; i < 8; ++i)
            #pragma unroll
            for (int r = 0; r < 4; ++r) {
                int row = m0 + wr * 128 + i * 16 + quad * 4 + r;
                #pragma unroll
                for (int j = 0; j < 4; ++j)
                    Cb[(long)row * NSP + n0 + wc * 64 + j * 16 + l15] = f2bf(acc[i][j][r]);
            }
    } else if (EPI == 1) {
        // softmax over d within each head's 64 rows, *0.125, write d-contiguous qhatT
        const int hbase = (m0 + wr * 128) >> 6;
        #pragma unroll
        for (int j = 0; j < 4; ++j) {
            int col = n0 + wc * 64 + j * 16 + l15;
            #pragma unroll
            for (int ih = 0; ih < 2; ++ih) {
                float mx = -3.4e38f;
                #pragma unroll
                for (int ii = 0; ii < 4; ++ii)
                    #pragma unroll
                    for (int r = 0; r < 4; ++r) mx = fmaxf(mx, acc[ih * 4 + ii][j][r]);
                mx = fmaxf(mx, __shfl_xor(mx, 16));
                mx = fmaxf(mx, __shfl_xor(mx, 32));
                float sm = 0.f;
                #pragma unroll
                for (int ii = 0; ii < 4; ++ii)
                    #pragma unroll
                    for (int r = 0; r < 4; ++r) {
                        float p = __expf(acc[ih * 4 + ii][j][r] - mx);
                        acc[ih * 4 + ii][j][r] = p;
                        sm += p;
                    }
                sm += __shfl_xor(sm, 16);
                sm += __shfl_xor(sm, 32);
                float rsc = 0.125f / sm;
                unsigned short* op = C + ((long)(b * 8 + hbase + ih) * NSP + col) * 64 + quad * 4;
                #pragma unroll
                for (int ii = 0; ii < 4; ++ii) {
                    u16x4 o;
                    #pragma unroll
                    for (int r = 0; r < 4; ++r) o[r] = f2bf(acc[ih * 4 + ii][j][r] * rsc);
                    *(u16x4*)(op + ii * 16) = o;
                }
            }
        }
    } else {
        unsigned short* Cb = C + (long)b * c_bstride;
        #pragma unroll
        for (int i = 0; i < 8; ++i)
            #pragma unroll
            for (int r = 0; r < 4; ++r) {
                float bv = bias[m0 + wr * 128 + i * 16 + quad * 4 + r];
                #pragma unroll
                for (int j = 0; j < 4; ++j) acc[i][j][r] += bv;
            }
        #pragma unroll
        for (int i = 0; i < 8; ++i)
            #pragma unroll
            for (int r = 0; r < 4; ++r) {
                int row = m0 + wr * 128 + i * 16 + quad * 4 + r;
                #pragma unroll
                for (int j = 0; j < 4; ++j)
                    Cb[(long)row * NSP + n0 + wc * 64 + j * 16 + l15] = f2bf(acc[i][j][r]);
            }
        float* sb = ssq + (long)b * NSP;
        #pragma unroll
        for (int j = 0; j < 4; ++j) {
            float p = 0.f;
            #pragma unroll
            for (int i = 0; i < 8; ++i)
                #pragma unroll
                for (int r = 0; r < 4; ++r) p += acc[i][j][r] * acc[i][j][r];
            p += __shfl_xor(p, 16);
            p += __shfl_xor(p, 32);
            if (quad == 0) atomicAdd(sb + n0 + wc * 64 + j * 16 + l15, p);
        }
    }
}

// ---------------- k softmax stats per (b,row): max, 1/sum(exp)
__global__ __launch_bounds__(256) void kstats_k(const unsigned short* __restrict__ kv,
                                                float* __restrict__ kst) {
    __shared__ float red[8];
    int row = blockIdx.x, b = blockIdx.y, t = threadIdx.x;
    int wave = t >> 6, lane = t & 63;
    const unsigned short* base = kv + ((long)b * 1024 + row) * NSP;
    float v[16];
    u16x8 a0 = *(const u16x8*)(base + t * 16);
    u16x8 a1 = *(const u16x8*)(base + t * 16 + 8);
    #pragma unroll
    for (int e = 0; e < 8; ++e) { v[e] = bf2f(a0[e]); v[8 + e] = bf2f(a1[e]); }
    float mx = v[0];
    #pragma unroll
    for (int e = 1; e < 16; ++e) mx = fmaxf(mx, v[e]);
    #pragma unroll
    for (int off = 32; off; off >>= 1) mx = fmaxf(mx, __shfl_xor(mx, off));
    if (lane == 0) red[wave] = mx;
    __syncthreads();
    mx = fmaxf(fmaxf(red[0], red[1]), fmaxf(red[2], red[3]));
    float sm = 0.f;
    #pragma unroll
    for (int e = 0; e < 16; ++e) sm += __expf(v[e] - mx);
    #pragma unroll
    for (int off = 32; off; off >>= 1) sm += __shfl_xor(sm, off);
    if (lane == 0) red[4 + wave] = sm;
    __syncthreads();
    if (t == 0) {
        float s = red[4] + red[5] + red[6] + red[7];
        kst[((long)b * 512 + row) * 2]     = mx;
        kst[((long)b * 512 + row) * 2 + 1] = 1.f / s;
    }
}

// ---------------- ctxP[slice][bh][e*64+d] = sum_{n in slice} khat[d,n]*v[e,n]
__global__ __launch_bounds__(256, 2) void context_kernel(const unsigned short* __restrict__ kv,
                                                         const float* __restrict__ kst,
                                                         float* __restrict__ ctxP) {
    alignas(16) __shared__ unsigned short Ks[64 * 256];   // 32 KB, swizzled
    alignas(16) __shared__ unsigned short Vs[64 * 256];   // 32 KB, swizzled
    int bh = blockIdx.x, b = bh >> 3, h = bh & 7;
    int t = threadIdx.x, wave = t >> 6, lane = t & 63, l15 = lane & 15, quad = lane >> 4;
    const unsigned short* kp = kv + ((long)b * 1024 + h * 64) * NSP;
    const unsigned short* vp = kv + ((long)b * 1024 + 512 + h * 64) * NSP;
    float mxu[8], rsu[8];
    #pragma unroll
    for (int u = 0; u < 8; ++u) {
        int row = u * 8 + (t >> 5);
        mxu[u] = kst[((long)b * 512 + h * 64 + row) * 2];
        rsu[u] = kst[((long)b * 512 + h * 64 + row) * 2 + 1];
    }
    f32x4 acc[4] = {};
    for (int tile = 0; tile < 4; ++tile) {
        int n0 = blockIdx.y * 1024 + tile * 256;
        #pragma unroll
        for (int is = 0; is < 8; ++is) {
            int cidx = (wave * 8 + is) * 64 + lane;       // 16B-chunk index 0..2047
            int row = cidx >> 5, cq = cidx & 31;
            int sc = (cq ^ (row & 7)) * 8;                // shorts
            gload16(kp + (long)row * NSP + n0 + sc, Ks + (wave * 8 + is) * 512);
            gload16(vp + (long)row * NSP + n0 + sc, Vs + (wave * 8 + is) * 512);
        }
        __syncthreads();
        #pragma unroll
        for (int u = 0; u < 8; ++u) {
            unsigned short* p = Ks + ((u * 256 + t) * 8);
            u16x8 v = *(const u16x8*)p;
            u16x8 o;
            #pragma unroll
            for (int e = 0; e < 8; ++e)
                o[e] = f2bf(__expf(bf2f(v[e]) - mxu[u]) * rsu[u]);
            *(u16x8*)p = o;
        }
        __syncthreads();
        #pragma unroll
        for (int ks = 0; ks < 8; ++ks) {
            s16x8 af[4], bfr;
            #pragma unroll
            for (int i = 0; i < 4; ++i) {
                int row = i * 16 + l15;
                af[i] = *(const s16x8*)(Ks + row * 256 + (((ks * 4 + quad) ^ (row & 7)) * 8));
            }
            {
                int row = wave * 16 + l15;
                bfr = *(const s16x8*)(Vs + row * 256 + (((ks * 4 + quad) ^ (row & 7)) * 8));
            }
            #pragma unroll
            for (int i = 0; i < 4; ++i)
                acc[i] = __builtin_amdgcn_mfma_f32_16x16x32_bf16(af[i], bfr, acc[i], 0, 0, 0);
        }
        __syncthreads();
    }
    float* cp = ctxP + ((long)blockIdx.y * 128 + bh) * 4096;
    #pragma unroll
    for (int i = 0; i < 4; ++i)
        *(f32x4*)(cp + (wave * 16 + l15) * 64 + i * 16 + quad * 4) = acc[i];
}

// ---------------- ctxT = sum over slices of ctxP
__global__ __launch_bounds__(256) void ctxreduce_k(const float* __restrict__ ctxP,
                                                   float* __restrict__ ctxT) {
    long i = ((long)blockIdx.x * 256 + threadIdx.x) * 4;
    f32x4 s = *(const f32x4*)(ctxP + i);
    #pragma unroll
    for (int sl = 1; sl < CTX_SLICES; ++sl) {
        f32x4 v = *(const f32x4*)(ctxP + (long)sl * 128 * 4096 + i);
        s += v;
    }
    *(f32x4*)(ctxT + i) = s;
}

// ---------------- attnT[b][n][h*64+e] = sum_d ctxT[e][d]*qhatT[n][d]   (MFMA)
__global__ __launch_bounds__(256) void attnout_kernel(const float* __restrict__ ctxT,
                                                      const unsigned short* __restrict__ qhatT,
                                                      unsigned short* __restrict__ attnT) {
    int bh = blockIdx.x, b = bh >> 3, h = bh & 7;
    int t = threadIdx.x, wave = t >> 6, lane = t & 63, l15 = lane & 15, quad = lane >> 4;
    int n0 = blockIdx.y * 256 + wave * 64;
    const float* cb = ctxT + (long)bh * 4096;
    s16x8 af[2][4];
    #pragma unroll
    for (int ks = 0; ks < 2; ++ks)
        #pragma unroll
        for (int i = 0; i < 4; ++i) {
            const float* src = cb + (i * 16 + l15) * 64 + ks * 32 + quad * 8;
            s16x8 a;
            #pragma unroll
            for (int e = 0; e < 8; ++e) a[e] = (short)f2bf(src[e]);
            af[ks][i] = a;
        }
    f32x4 acc[4][4] = {};
    const unsigned short* qb = qhatT + (long)bh * NSP * 64;
    #pragma unroll
    for (int ks = 0; ks < 2; ++ks) {
        s16x8 bfr[4];
        #pragma unroll
        for (int j = 0; j < 4; ++j)
            bfr[j] = *(const s16x8*)(qb + (long)(n0 + j * 16 + l15) * 64 + ks * 32 + quad * 8);
        #pragma unroll
        for (int i = 0; i < 4; ++i)
            #pragma unroll
            for (int j = 0; j < 4; ++j)
                acc[i][j] = __builtin_amdgcn_mfma_f32_16x16x32_bf16(af[ks][i], bfr[j], acc[i][j], 0, 0, 0);
    }
    #pragma unroll
    for (int i = 0; i < 4; ++i)
        #pragma unroll
        for (int j = 0; j < 4; ++j) {
            int n = n0 + j * 16 + l15;
            u16x4 o;
            #pragma unroll
            for (int r = 0; r < 4; ++r) o[r] = f2bf(acc[i][j][r]);
            *(u16x4*)(attnT + ((long)b * NSP + n) * CDIM + h * 64 + i * 16 + quad * 4) = o;
        }
}

// ---------------- out fp32 = y_bf16 * (SQRTC*rsqrt(ssq[b,n])) * g2[c]
__global__ __launch_bounds__(256) void final_kernel(const unsigned short* __restrict__ y,
                                                    const float* __restrict__ g2,
                                                    const float* __restrict__ ssq,
                                                    float* __restrict__ out) {
    long flat = ((long)blockIdx.x * 256 + threadIdx.x) * 4;
    int b = (int)(flat >> 21);
    int rem = (int)(flat & ((1 << 21) - 1));
    int c = rem >> 12, n = rem & 4095;
    u16x4 u = *(const u16x4*)(y + flat);
    f32x4 sq = *(const f32x4*)(ssq + b * NSP + n);
    float g = g2[c];
    f32x4 ov;
    #pragma unroll
    for (int s = 0; s < 4; ++s)
        ov[s] = bf2f(u[s]) * (SQRTC * rsqrtf(fmaxf(sq[s], 1e-24f))) * g;
    *(f32x4*)(out + flat) = ov;
}

extern "C" void kernel_launch(void* const* d_in, const int* in_sizes, int n_in,
                              void* d_out, int out_size, void* d_ws, size_t ws_size,
                              hipStream_t stream) {
    (void)in_sizes; (void)n_in; (void)out_size; (void)ws_size;
    const float* x     = (const float*)d_in[0];
    const float* g1    = (const float*)d_in[1];
    const float* w_qkv = (const float*)d_in[2];
    const float* w_out = (const float*)d_in[3];
    const float* b_out = (const float*)d_in[4];
    const float* g2    = (const float*)d_in[5];
    float* out = (float*)d_out;

    char* ws = (char*)d_ws;
    const size_t MB = 1024 * 1024;
    // [0,64): xnt -> attnT.  [64,192): kv; y reuses [64,128), qhatT at [128,192).
    unsigned short* xnt   = (unsigned short*)(ws);
    unsigned short* attnT = xnt;
    unsigned short* kv    = (unsigned short*)(ws + 64 * MB);
    unsigned short* y     = kv;
    unsigned short* qhatT = (unsigned short*)(ws + 128 * MB);
    unsigned short* wqkvb = (unsigned short*)(ws + 192 * MB);            // 1.5 MiB
    unsigned short* woutb = (unsigned short*)(ws + 192 * MB + 1536 * 1024); // 0.5 MiB
    float* inv1 = (float*)(ws + 194 * MB);
    float* ssq  = (float*)(ws + 194 * MB + 256 * 1024);                  // 256 KB
    float* kst  = (float*)(ws + 194 * MB + 512 * 1024);
    float* ctxT = (float*)(ws + 195 * MB);                               // 2 MiB
    float* ctxP = (float*)(ws + 197 * MB);                               // 8 MiB -> ends 205 MiB

    hipLaunchKernelGGL(convert_k, dim3(768), dim3(256), 0, stream, w_qkv, wqkvb, 196608);
    hipLaunchKernelGGL(convert_k, dim3(256), dim3(256), 0, stream, w_out, woutb, 65536);
    hipMemsetAsync(ssq, 0, (size_t)B_ * NSP * 4, stream);
    hipLaunchKernelGGL(inv_stats_x_k, dim3(64, 16), dim3(256), 0, stream, x, inv1);
    hipLaunchKernelGGL(xnt_kernel, dim3(64, 8, 16), dim3(256), 0, stream, x, g1, inv1, xnt);
    // kv GEMM: rows 512..1535 of wqkvb, M=1024
    hipLaunchKernelGGL((gemm256_kernel<0>), dim3(16, 4, 16), dim3(512), 0, stream,
                       wqkvb + 512 * GK, xnt, kv, (const float*)nullptr, (float*)nullptr,
                       (long)NSP * CDIM, (long)1024 * NSP);
    hipLaunchKernelGGL(kstats_k, dim3(512, 16), dim3(256), 0, stream, kv, kst);
    hipLaunchKernelGGL(context_kernel, dim3(128, CTX_SLICES), dim3(256), 0, stream, kv, kst, ctxP);
    hipLaunchKernelGGL(ctxreduce_k, dim3(512), dim3(256), 0, stream, ctxP, ctxT);
    // q GEMM (rows 0..511) with fused softmax epilogue -> qhatT
    hipLaunchKernelGGL((gemm256_kernel<1>), dim3(16, 2, 16), dim3(512), 0, stream,
                       wqkvb, xnt, qhatT, (const float*)nullptr, (float*)nullptr,
                       (long)NSP * CDIM, 0L);
    hipLaunchKernelGGL(attnout_kernel, dim3(128, 16), dim3(256), 0, stream, ctxT, qhatT, attnT);
    // out GEMM with bias + fused column-ssq accumulation
    hipLaunchKernelGGL((gemm256_kernel<2>), dim3(16, 2, 16), dim3(512), 0, stream,
                       woutb, attnT, y, b_out, ssq, (long)NSP * CDIM, (long)512 * NSP);
    hipLaunchKernelGGL(final_kernel, dim3(32768), dim3(256), 0, stream, y, g2, ssq, out);
}

// Round 5
// 569.906 us; speedup vs baseline: 1.3137x; 1.0025x over previous
//
#include <hip/hip_runtime.h>

#define B_    16
#define CDIM  512
#define NSP   4096
#define GK    512
#define SQRTC 22.62741699796952f
#define CTX_SLICES 4

typedef __attribute__((ext_vector_type(4))) float f32x4;
typedef __attribute__((ext_vector_type(8))) short s16x8;
typedef __attribute__((ext_vector_type(4))) unsigned short u16x4;
typedef __attribute__((ext_vector_type(8))) unsigned short u16x8;

__device__ __forceinline__ float bf2f(unsigned short u) {
    union { unsigned int i; float f; } v; v.i = ((unsigned int)u) << 16; return v.f;
}
__device__ __forceinline__ unsigned short f2bf(float f) {
    union { float fl; unsigned int i; } v; v.fl = f;
    unsigned int r = v.i + 0x7FFFu + ((v.i >> 16) & 1u);
    return (unsigned short)(r >> 16);
}

// async global -> LDS, 16B per lane. LDS dest is wave-uniform base; HW adds lane*16.
// Global source address IS per-lane -> swizzled layouts via pre-swizzled source.
__device__ __forceinline__ void gload16(const unsigned short* g, unsigned short* l) {
    __builtin_amdgcn_global_load_lds(
        (const __attribute__((address_space(1))) unsigned int*)g,
        (__attribute__((address_space(3))) unsigned int*)l,
        16, 0, 0);
}

// ---------------- fp32 -> bf16 weight conversion
__global__ __launch_bounds__(256) void convert_k(const float* __restrict__ in,
                                                 unsigned short* __restrict__ out, int n4) {
    int i = blockIdx.x * 256 + threadIdx.x;
    if (i >= n4) return;
    f32x4 v = *(const f32x4*)(in + (long)i * 4);
    u16x4 o;
    #pragma unroll
    for (int s = 0; s < 4; ++s) o[s] = f2bf(v[s]);
    *(u16x4*)(out + (long)i * 4) = o;
}

// ---------------- inv[b,n] = sqrt(512)/max(||x[b,:,n]||,eps), x fp32 [b,c,n]
__global__ __launch_bounds__(256) void inv_stats_x_k(const float* __restrict__ x,
                                                     float* __restrict__ inv) {
    __shared__ float red[16 * 64];
    int n0 = blockIdx.x * 64, b = blockIdx.y, t = threadIdx.x;
    int rg = t >> 4, c4 = (t & 15) * 4;
    const float* xb = x + (long)b * CDIM * NSP + n0 + c4;
    f32x4 ss = {0.f, 0.f, 0.f, 0.f};
    for (int c = rg; c < CDIM; c += 16) {
        f32x4 v = *(const f32x4*)(xb + (long)c * NSP);
        ss += v * v;
    }
    *(f32x4*)(red + rg * 64 + c4) = ss;
    __syncthreads();
    if (t < 64) {
        float s = 0.f;
        #pragma unroll
        for (int r = 0; r < 16; ++r) s += red[r * 64 + t];
        inv[b * NSP + n0 + t] = SQRTC / fmaxf(sqrtf(s), 1e-12f);
    }
}

// ---------------- xn_t[b][n][c] = x[b][c][n]*inv1[b,n]*g1[c]  (fp32 in, bf16 out, transpose)
__global__ __launch_bounds__(256) void xnt_kernel(const float* __restrict__ x,
                                                  const float* __restrict__ g1,
                                                  const float* __restrict__ inv,
                                                  unsigned short* __restrict__ xnt) {
    alignas(16) __shared__ float tile[64 * 68];
    int n0 = blockIdx.x * 64, c0 = blockIdx.y * 64, b = blockIdx.z;
    int t = threadIdx.x;
    #pragma unroll
    for (int it = 0; it < 4; ++it) {
        int idx = it * 256 + t;
        int r = idx >> 4, c4 = (idx & 15) * 4;          // r = c-row, c4 = n-col
        f32x4 v = *(const f32x4*)(x + (long)(b * CDIM + c0 + r) * NSP + n0 + c4);
        *(f32x4*)(tile + r * 68 + c4) = v;
    }
    __syncthreads();
    #pragma unroll
    for (int it = 0; it < 4; ++it) {
        int idx = it * 256 + t;
        int nr = idx >> 4, cc = (idx & 15) * 4;         // nr = n-row, cc = c-col
        float s = inv[b * NSP + n0 + nr];
        u16x4 o;
        #pragma unroll
        for (int si = 0; si < 4; ++si)
            o[si] = f2bf(tile[(cc + si) * 68 + nr] * s * g1[c0 + cc + si]);
        *(u16x4*)(xnt + (long)(b * NSP + n0 + nr) * CDIM + c0 + cc) = o;
    }
}

// ---------------- 256x256 MFMA GEMM, BK=32, 4-deep LDS pipeline, counted vmcnt.
// C[b][m][n] = A[m][:].Bt[b][n][:].  EPI: 0 = plain bf16 C (kv GEMM),
// 1 = softmax-over-d epilogue -> qhatT (q GEMM), 2 = +bias +column-ssq (out GEMM).
// Prefetch distance 3: stages kt+1,kt+2 stay in flight across barriers (vmcnt(8),
// never 0 in the main loop). Swizzle quad^((row>>1)&3) on 64B rows (measured 0-conflict).
template<int EPI>
__global__ __launch_bounds__(512, 2) void gemm256_kernel(
        const unsigned short* __restrict__ A, const unsigned short* __restrict__ Bt,
        unsigned short* __restrict__ C, const float* __restrict__ bias,
        float* __restrict__ ssq, long bt_bstride, long c_bstride) {
    alignas(16) __shared__ unsigned short As[4][256 * 32];   // 4 x 16 KB
    alignas(16) __shared__ unsigned short Bs[4][256 * 32];   // 4 x 16 KB
    const int t = threadIdx.x, lane = t & 63;
    const int l15 = lane & 15, quad = lane >> 4;
    const int wave = t >> 6, wr = wave >> 2, wc = wave & 3;   // 2 x 4 wave grid
    const int m0 = blockIdx.y * 256, n0 = blockIdx.x * 256, b = blockIdx.z;
    const unsigned short* Bb = Bt + (long)b * bt_bstride;

    // staging sources (kt-independent): per stage, 2 issues x (A,B), 16B/lane.
    // 16B-chunk idx = is*512+t; row = idx>>2, chunk-in-row cq = idx&3;
    // source chunk = cq ^ ((row>>1)&3)  (inverse swizzle; LDS dest stays linear)
    const unsigned short* aSrc[2];
    const unsigned short* bSrc[2];
    int wb[2];
    #pragma unroll
    for (int is = 0; is < 2; ++is) {
        int idx = is * 512 + t;
        int row = idx >> 2, cq = idx & 3;
        int sc = (cq ^ ((row >> 1) & 3)) * 8;
        aSrc[is] = A  + (long)(m0 + row) * GK + sc;
        bSrc[is] = Bb + (long)(n0 + row) * GK + sc;
        wb[is] = (is * 512 + (t & 448)) * 8;     // wave-uniform LDS base (shorts)
    }

    f32x4 acc[8][4] = {};

#define STAGE_T(kt_, buf_)                                        \
    {                                                             \
        int kb_ = (kt_) * 32;                                     \
        _Pragma("unroll")                                         \
        for (int is = 0; is < 2; ++is) {                          \
            gload16(aSrc[is] + kb_, &As[(buf_)][0] + wb[is]);     \
            gload16(bSrc[is] + kb_, &Bs[(buf_)][0] + wb[is]);     \
        }                                                         \
    }

#define COMPUTE_T(buf_)                                                         \
    {                                                                           \
        const unsigned short* Ab = &As[(buf_)][0];                              \
        const unsigned short* Bp = &Bs[(buf_)][0];                              \
        s16x8 af[8], bfv[4];                                                    \
        _Pragma("unroll")                                                       \
        for (int i = 0; i < 8; ++i) {                                           \
            int row = wr * 128 + i * 16 + l15;                                  \
            af[i] = *(const s16x8*)(Ab + row * 32 + ((quad ^ ((row >> 1) & 3)) * 8)); \
        }                                                                       \
        _Pragma("unroll")                                                       \
        for (int j = 0; j < 4; ++j) {                                           \
            int row = wc * 64 + j * 16 + l15;                                   \
            bfv[j] = *(const s16x8*)(Bp + row * 32 + ((quad ^ ((row >> 1) & 3)) * 8)); \
        }                                                                       \
        __builtin_amdgcn_s_setprio(1);                                          \
        _Pragma("unroll")                                                       \
        for (int i = 0; i < 8; ++i)                                             \
            _Pragma("unroll")                                                   \
            for (int j = 0; j < 4; ++j)                                         \
                acc[i][j] = __builtin_amdgcn_mfma_f32_16x16x32_bf16(af[i], bfv[j], acc[i][j], 0, 0, 0); \
        __builtin_amdgcn_s_setprio(0);                                          \
    }

    // prologue: stage tiles 0,1,2 (12 loads/thread in flight)
    STAGE_T(0, 0); STAGE_T(1, 1); STAGE_T(2, 2);

    #pragma unroll
    for (int kt = 0; kt < 14; ++kt) {
        // own stage-kt loads landed (<=8 outstanding: stages kt+1, kt+2)
        asm volatile("s_waitcnt vmcnt(8)" ::: "memory");
        __builtin_amdgcn_s_barrier();        // collectively: stage kt fully in LDS,
                                             // buf (kt+3)&3 = (kt-1)&3 free for reuse
        STAGE_T(kt + 3, (kt + 3) & 3);       // overlaps compute of kt
        COMPUTE_T(kt & 3);
    }
    asm volatile("s_waitcnt vmcnt(4)" ::: "memory");
    __builtin_amdgcn_s_barrier();
    COMPUTE_T(2);                            // kt = 14
    asm volatile("s_waitcnt vmcnt(0)" ::: "memory");
    __builtin_amdgcn_s_barrier();
    COMPUTE_T(3);                            // kt = 15

#undef STAGE_T
#undef COMPUTE_T

    if (EPI == 0) {
        unsigned short* Cb = C + (long)b * c_bstride;
        #pragma unroll
        for (int i = 0; i < 8; ++i)
            #pragma unroll
            for (int r = 0; r < 4; ++r) {
                int row = m0 + wr * 128 + i * 16 + quad * 4 + r;
                #pragma unroll
                for (int j = 0; j < 4; ++j)
                    Cb[(long)row * NSP + n0 + wc * 64 + j * 16 + l15] = f2bf(acc[i][j][r]);
            }
    } else if (EPI == 1) {
        // softmax over d within each head's 64 rows, *0.125, write d-contiguous qhatT
        const int hbase = (m0 + wr * 128) >> 6;
        #pragma unroll
        for (int j = 0; j < 4; ++j) {
            int col = n0 + wc * 64 + j * 16 + l15;
            #pragma unroll
            for (int ih = 0; ih < 2; ++ih) {
                float mx = -3.4e38f;
                #pragma unroll
                for (int ii = 0; ii < 4; ++ii)
                    #pragma unroll
                    for (int r = 0; r < 4; ++r) mx = fmaxf(mx, acc[ih * 4 + ii][j][r]);
                mx = fmaxf(mx, __shfl_xor(mx, 16));
                mx = fmaxf(mx, __shfl_xor(mx, 32));
                float sm = 0.f;
                #pragma unroll
                for (int ii = 0; ii < 4; ++ii)
                    #pragma unroll
                    for (int r = 0; r < 4; ++r) {
                        float p = __expf(acc[ih * 4 + ii][j][r] - mx);
                        acc[ih * 4 + ii][j][r] = p;
                        sm += p;
                    }
                sm += __shfl_xor(sm, 16);
                sm += __shfl_xor(sm, 32);
                float rsc = 0.125f / sm;
                unsigned short* op = C + ((long)(b * 8 + hbase + ih) * NSP + col) * 64 + quad * 4;
                #pragma unroll
                for (int ii = 0; ii < 4; ++ii) {
                    u16x4 o;
                    #pragma unroll
                    for (int r = 0; r < 4; ++r) o[r] = f2bf(acc[ih * 4 + ii][j][r] * rsc);
                    *(u16x4*)(op + ii * 16) = o;
                }
            }
        }
    } else {
        unsigned short* Cb = C + (long)b * c_bstride;
        #pragma unroll
        for (int i = 0; i < 8; ++i)
            #pragma unroll
            for (int r = 0; r < 4; ++r) {
                float bv = bias[m0 + wr * 128 + i * 16 + quad * 4 + r];
                #pragma unroll
                for (int j = 0; j < 4; ++j) acc[i][j][r] += bv;
            }
        #pragma unroll
        for (int i = 0; i < 8; ++i)
            #pragma unroll
            for (int r = 0; r < 4; ++r) {
                int row = m0 + wr * 128 + i * 16 + quad * 4 + r;
                #pragma unroll
                for (int j = 0; j < 4; ++j)
                    Cb[(long)row * NSP + n0 + wc * 64 + j * 16 + l15] = f2bf(acc[i][j][r]);
            }
        float* sb = ssq + (long)b * NSP;
        #pragma unroll
        for (int j = 0; j < 4; ++j) {
            float p = 0.f;
            #pragma unroll
            for (int i = 0; i < 8; ++i)
                #pragma unroll
                for (int r = 0; r < 4; ++r) p += acc[i][j][r] * acc[i][j][r];
            p += __shfl_xor(p, 16);
            p += __shfl_xor(p, 32);
            if (quad == 0) atomicAdd(sb + n0 + wc * 64 + j * 16 + l15, p);
        }
    }
}

// ---------------- k softmax stats per (b,row): max, 1/sum(exp)
__global__ __launch_bounds__(256) void kstats_k(const unsigned short* __restrict__ kv,
                                                float* __restrict__ kst) {
    __shared__ float red[8];
    int row = blockIdx.x, b = blockIdx.y, t = threadIdx.x;
    int wave = t >> 6, lane = t & 63;
    const unsigned short* base = kv + ((long)b * 1024 + row) * NSP;
    float v[16];
    u16x8 a0 = *(const u16x8*)(base + t * 16);
    u16x8 a1 = *(const u16x8*)(base + t * 16 + 8);
    #pragma unroll
    for (int e = 0; e < 8; ++e) { v[e] = bf2f(a0[e]); v[8 + e] = bf2f(a1[e]); }
    float mx = v[0];
    #pragma unroll
    for (int e = 1; e < 16; ++e) mx = fmaxf(mx, v[e]);
    #pragma unroll
    for (int off = 32; off; off >>= 1) mx = fmaxf(mx, __shfl_xor(mx, off));
    if (lane == 0) red[wave] = mx;
    __syncthreads();
    mx = fmaxf(fmaxf(red[0], red[1]), fmaxf(red[2], red[3]));
    float sm = 0.f;
    #pragma unroll
    for (int e = 0; e < 16; ++e) sm += __expf(v[e] - mx);
    #pragma unroll
    for (int off = 32; off; off >>= 1) sm += __shfl_xor(sm, off);
    if (lane == 0) red[4 + wave] = sm;
    __syncthreads();
    if (t == 0) {
        float s = red[4] + red[5] + red[6] + red[7];
        kst[((long)b * 512 + row) * 2]     = mx;
        kst[((long)b * 512 + row) * 2 + 1] = 1.f / s;
    }
}

// ---------------- ctxP[slice][bh][e*64+d] = sum_{n in slice} khat[d,n]*v[e,n]
__global__ __launch_bounds__(256, 2) void context_kernel(const unsigned short* __restrict__ kv,
                                                         const float* __restrict__ kst,
                                                         float* __restrict__ ctxP) {
    alignas(16) __shared__ unsigned short Ks[64 * 256];   // 32 KB, swizzled
    alignas(16) __shared__ unsigned short Vs[64 * 256];   // 32 KB, swizzled
    int bh = blockIdx.x, b = bh >> 3, h = bh & 7;
    int t = threadIdx.x, wave = t >> 6, lane = t & 63, l15 = lane & 15, quad = lane >> 4;
    const unsigned short* kp = kv + ((long)b * 1024 + h * 64) * NSP;
    const unsigned short* vp = kv + ((long)b * 1024 + 512 + h * 64) * NSP;
    float mxu[8], rsu[8];
    #pragma unroll
    for (int u = 0; u < 8; ++u) {
        int row = u * 8 + (t >> 5);
        mxu[u] = kst[((long)b * 512 + h * 64 + row) * 2];
        rsu[u] = kst[((long)b * 512 + h * 64 + row) * 2 + 1];
    }
    f32x4 acc[4] = {};
    for (int tile = 0; tile < 4; ++tile) {
        int n0 = blockIdx.y * 1024 + tile * 256;
        #pragma unroll
        for (int is = 0; is < 8; ++is) {
            int cidx = (wave * 8 + is) * 64 + lane;       // 16B-chunk index 0..2047
            int row = cidx >> 5, cq = cidx & 31;
            int sc = (cq ^ (row & 7)) * 8;                // shorts
            gload16(kp + (long)row * NSP + n0 + sc, Ks + (wave * 8 + is) * 512);
            gload16(vp + (long)row * NSP + n0 + sc, Vs + (wave * 8 + is) * 512);
        }
        __syncthreads();
        #pragma unroll
        for (int u = 0; u < 8; ++u) {
            unsigned short* p = Ks + ((u * 256 + t) * 8);
            u16x8 v = *(const u16x8*)p;
            u16x8 o;
            #pragma unroll
            for (int e = 0; e < 8; ++e)
                o[e] = f2bf(__expf(bf2f(v[e]) - mxu[u]) * rsu[u]);
            *(u16x8*)p = o;
        }
        __syncthreads();
        #pragma unroll
        for (int ks = 0; ks < 8; ++ks) {
            s16x8 af[4], bfr;
            #pragma unroll
            for (int i = 0; i < 4; ++i) {
                int row = i * 16 + l15;
                af[i] = *(const s16x8*)(Ks + row * 256 + (((ks * 4 + quad) ^ (row & 7)) * 8));
            }
            {
                int row = wave * 16 + l15;
                bfr = *(const s16x8*)(Vs + row * 256 + (((ks * 4 + quad) ^ (row & 7)) * 8));
            }
            #pragma unroll
            for (int i = 0; i < 4; ++i)
                acc[i] = __builtin_amdgcn_mfma_f32_16x16x32_bf16(af[i], bfr, acc[i], 0, 0, 0);
        }
        __syncthreads();
    }
    float* cp = ctxP + ((long)blockIdx.y * 128 + bh) * 4096;
    #pragma unroll
    for (int i = 0; i < 4; ++i)
        *(f32x4*)(cp + (wave * 16 + l15) * 64 + i * 16 + quad * 4) = acc[i];
}

// ---------------- ctxT = sum over slices of ctxP
__global__ __launch_bounds__(256) void ctxreduce_k(const float* __restrict__ ctxP,
                                                   float* __restrict__ ctxT) {
    long i = ((long)blockIdx.x * 256 + threadIdx.x) * 4;
    f32x4 s = *(const f32x4*)(ctxP + i);
    #pragma unroll
    for (int sl = 1; sl < CTX_SLICES; ++sl) {
        f32x4 v = *(const f32x4*)(ctxP + (long)sl * 128 * 4096 + i);
        s += v;
    }
    *(f32x4*)(ctxT + i) = s;
}

// ---------------- attnT[b][n][h*64+e] = sum_d ctxT[e][d]*qhatT[n][d]   (MFMA)
__global__ __launch_bounds__(256) void attnout_kernel(const float* __restrict__ ctxT,
                                                      const unsigned short* __restrict__ qhatT,
                                                      unsigned short* __restrict__ attnT) {
    int bh = blockIdx.x, b = bh >> 3, h = bh & 7;
    int t = threadIdx.x, wave = t >> 6, lane = t & 63, l15 = lane & 15, quad = lane >> 4;
    int n0 = blockIdx.y * 256 + wave * 64;
    const float* cb = ctxT + (long)bh * 4096;
    s16x8 af[2][4];
    #pragma unroll
    for (int ks = 0; ks < 2; ++ks)
        #pragma unroll
        for (int i = 0; i < 4; ++i) {
            const float* src = cb + (i * 16 + l15) * 64 + ks * 32 + quad * 8;
            s16x8 a;
            #pragma unroll
            for (int e = 0; e < 8; ++e) a[e] = (short)f2bf(src[e]);
            af[ks][i] = a;
        }
    f32x4 acc[4][4] = {};
    const unsigned short* qb = qhatT + (long)bh * NSP * 64;
    #pragma unroll
    for (int ks = 0; ks < 2; ++ks) {
        s16x8 bfr[4];
        #pragma unroll
        for (int j = 0; j < 4; ++j)
            bfr[j] = *(const s16x8*)(qb + (long)(n0 + j * 16 + l15) * 64 + ks * 32 + quad * 8);
        #pragma unroll
        for (int i = 0; i < 4; ++i)
            #pragma unroll
            for (int j = 0; j < 4; ++j)
                acc[i][j] = __builtin_amdgcn_mfma_f32_16x16x32_bf16(af[ks][i], bfr[j], acc[i][j], 0, 0, 0);
    }
    #pragma unroll
    for (int i = 0; i < 4; ++i)
        #pragma unroll
        for (int j = 0; j < 4; ++j) {
            int n = n0 + j * 16 + l15;
            u16x4 o;
            #pragma unroll
            for (int r = 0; r < 4; ++r) o[r] = f2bf(acc[i][j][r]);
            *(u16x4*)(attnT + ((long)b * NSP + n) * CDIM + h * 64 + i * 16 + quad * 4) = o;
        }
}

// ---------------- out fp32 = y_bf16 * (SQRTC*rsqrt(ssq[b,n])) * g2[c]
__global__ __launch_bounds__(256) void final_kernel(const unsigned short* __restrict__ y,
                                                    const float* __restrict__ g2,
                                                    const float* __restrict__ ssq,
                                                    float* __restrict__ out) {
    long flat = ((long)blockIdx.x * 256 + threadIdx.x) * 4;
    int b = (int)(flat >> 21);
    int rem = (int)(flat & ((1 << 21) - 1));
    int c = rem >> 12, n = rem & 4095;
    u16x4 u = *(const u16x4*)(y + flat);
    f32x4 sq = *(const f32x4*)(ssq + b * NSP + n);
    float g = g2[c];
    f32x4 ov;
    #pragma unroll
    for (int s = 0; s < 4; ++s)
        ov[s] = bf2f(u[s]) * (SQRTC * rsqrtf(fmaxf(sq[s], 1e-24f))) * g;
    *(f32x4*)(out + flat) = ov;
}

extern "C" void kernel_launch(void* const* d_in, const int* in_sizes, int n_in,
                              void* d_out, int out_size, void* d_ws, size_t ws_size,
                              hipStream_t stream) {
    (void)in_sizes; (void)n_in; (void)out_size; (void)ws_size;
    const float* x     = (const float*)d_in[0];
    const float* g1    = (const float*)d_in[1];
    const float* w_qkv = (const float*)d_in[2];
    const float* w_out = (const float*)d_in[3];
    const float* b_out = (const float*)d_in[4];
    const float* g2    = (const float*)d_in[5];
    float* out = (float*)d_out;

    char* ws = (char*)d_ws;
    const size_t MB = 1024 * 1024;
    // [0,64): xnt -> attnT.  [64,192): kv; y reuses [64,128), qhatT at [128,192).
    unsigned short* xnt   = (unsigned short*)(ws);
    unsigned short* attnT = xnt;
    unsigned short* kv    = (unsigned short*)(ws + 64 * MB);
    unsigned short* y     = kv;
    unsigned short* qhatT = (unsigned short*)(ws + 128 * MB);
    unsigned short* wqkvb = (unsigned short*)(ws + 192 * MB);            // 1.5 MiB
    unsigned short* woutb = (unsigned short*)(ws + 192 * MB + 1536 * 1024); // 0.5 MiB
    float* inv1 = (float*)(ws + 194 * MB);
    float* ssq  = (float*)(ws + 194 * MB + 256 * 1024);                  // 256 KB
    float* kst  = (float*)(ws + 194 * MB + 512 * 1024);
    float* ctxT = (float*)(ws + 195 * MB);                               // 2 MiB
    float* ctxP = (float*)(ws + 197 * MB);                               // 8 MiB -> ends 205 MiB

    hipLaunchKernelGGL(convert_k, dim3(768), dim3(256), 0, stream, w_qkv, wqkvb, 196608);
    hipLaunchKernelGGL(convert_k, dim3(256), dim3(256), 0, stream, w_out, woutb, 65536);
    hipMemsetAsync(ssq, 0, (size_t)B_ * NSP * 4, stream);
    hipLaunchKernelGGL(inv_stats_x_k, dim3(64, 16), dim3(256), 0, stream, x, inv1);
    hipLaunchKernelGGL(xnt_kernel, dim3(64, 8, 16), dim3(256), 0, stream, x, g1, inv1, xnt);
    // kv GEMM: rows 512..1535 of wqkvb, M=1024
    hipLaunchKernelGGL((gemm256_kernel<0>), dim3(16, 4, 16), dim3(512), 0, stream,
                       wqkvb + 512 * GK, xnt, kv, (const float*)nullptr, (float*)nullptr,
                       (long)NSP * CDIM, (long)1024 * NSP);
    hipLaunchKernelGGL(kstats_k, dim3(512, 16), dim3(256), 0, stream, kv, kst);
    hipLaunchKernelGGL(context_kernel, dim3(128, CTX_SLICES), dim3(256), 0, stream, kv, kst, ctxP);
    hipLaunchKernelGGL(ctxreduce_k, dim3(512), dim3(256), 0, stream, ctxP, ctxT);
    // q GEMM (rows 0..511) with fused softmax epilogue -> qhatT
    hipLaunchKernelGGL((gemm256_kernel<1>), dim3(16, 2, 16), dim3(512), 0, stream,
                       wqkvb, xnt, qhatT, (const float*)nullptr, (float*)nullptr,
                       (long)NSP * CDIM, 0L);
    hipLaunchKernelGGL(attnout_kernel, dim3(128, 16), dim3(256), 0, stream, ctxT, qhatT, attnT);
    // out GEMM with bias + fused column-ssq accumulation
    hipLaunchKernelGGL((gemm256_kernel<2>), dim3(16, 2, 16), dim3(512), 0, stream,
                       woutb, attnT, y, b_out, ssq, (long)NSP * CDIM, (long)512 * NSP);
    hipLaunchKernelGGL(final_kernel, dim3(32768), dim3(256), 0, stream, y, g2, ssq, out);
}

// Round 6
// 566.570 us; speedup vs baseline: 1.3214x; 1.0059x over previous
//
#include <hip/hip_runtime.h>

#define B_    16
#define CDIM  512
#define NSP   4096
#define GK    512
#define SQRTC 22.62741699796952f
#define CTX_SLICES 4

typedef __attribute__((ext_vector_type(4))) float f32x4;
typedef __attribute__((ext_vector_type(8))) short s16x8;
typedef __attribute__((ext_vector_type(4))) unsigned short u16x4;
typedef __attribute__((ext_vector_type(8))) unsigned short u16x8;

__device__ __forceinline__ float bf2f(unsigned short u) {
    union { unsigned int i; float f; } v; v.i = ((unsigned int)u) << 16; return v.f;
}
__device__ __forceinline__ unsigned short f2bf(float f) {
    union { float fl; unsigned int i; } v; v.fl = f;
    unsigned int r = v.i + 0x7FFFu + ((v.i >> 16) & 1u);
    return (unsigned short)(r >> 16);
}

// async global -> LDS, 16B per lane. LDS dest is wave-uniform base; HW adds lane*16.
// Global source address IS per-lane -> swizzled layouts via pre-swizzled source.
__device__ __forceinline__ void gload16(const unsigned short* g, unsigned short* l) {
    __builtin_amdgcn_global_load_lds(
        (const __attribute__((address_space(1))) unsigned int*)g,
        (__attribute__((address_space(3))) unsigned int*)l,
        16, 0, 0);
}

#define VMW(n_)  asm volatile("s_waitcnt vmcnt(" #n_ ")" ::: "memory")
#define BARR()   asm volatile("s_barrier" ::: "memory")
#define LGKM0()  do { asm volatile("s_waitcnt lgkmcnt(0)" ::: "memory"); \
                      __builtin_amdgcn_sched_barrier(0); } while (0)

// ---------------- fp32 -> bf16 weight conversion
__global__ __launch_bounds__(256) void convert_k(const float* __restrict__ in,
                                                 unsigned short* __restrict__ out, int n4) {
    int i = blockIdx.x * 256 + threadIdx.x;
    if (i >= n4) return;
    f32x4 v = *(const f32x4*)(in + (long)i * 4);
    u16x4 o;
    #pragma unroll
    for (int s = 0; s < 4; ++s) o[s] = f2bf(v[s]);
    *(u16x4*)(out + (long)i * 4) = o;
}

// ---------------- inv[b,n] = sqrt(512)/max(||x[b,:,n]||,eps), x fp32 [b,c,n]
__global__ __launch_bounds__(256) void inv_stats_x_k(const float* __restrict__ x,
                                                     float* __restrict__ inv) {
    __shared__ float red[16 * 64];
    int n0 = blockIdx.x * 64, b = blockIdx.y, t = threadIdx.x;
    int rg = t >> 4, c4 = (t & 15) * 4;
    const float* xb = x + (long)b * CDIM * NSP + n0 + c4;
    f32x4 ss = {0.f, 0.f, 0.f, 0.f};
    for (int c = rg; c < CDIM; c += 16) {
        f32x4 v = *(const f32x4*)(xb + (long)c * NSP);
        ss += v * v;
    }
    *(f32x4*)(red + rg * 64 + c4) = ss;
    __syncthreads();
    if (t < 64) {
        float s = 0.f;
        #pragma unroll
        for (int r = 0; r < 16; ++r) s += red[r * 64 + t];
        inv[b * NSP + n0 + t] = SQRTC / fmaxf(sqrtf(s), 1e-12f);
    }
}

// ---------------- xn_t[b][n][c] = x[b][c][n]*inv1[b,n]*g1[c]  (fp32 in, bf16 out, transpose)
__global__ __launch_bounds__(256) void xnt_kernel(const float* __restrict__ x,
                                                  const float* __restrict__ g1,
                                                  const float* __restrict__ inv,
                                                  unsigned short* __restrict__ xnt) {
    alignas(16) __shared__ float tile[64 * 68];
    int n0 = blockIdx.x * 64, c0 = blockIdx.y * 64, b = blockIdx.z;
    int t = threadIdx.x;
    #pragma unroll
    for (int it = 0; it < 4; ++it) {
        int idx = it * 256 + t;
        int r = idx >> 4, c4 = (idx & 15) * 4;          // r = c-row, c4 = n-col
        f32x4 v = *(const f32x4*)(x + (long)(b * CDIM + c0 + r) * NSP + n0 + c4);
        *(f32x4*)(tile + r * 68 + c4) = v;
    }
    __syncthreads();
    #pragma unroll
    for (int it = 0; it < 4; ++it) {
        int idx = it * 256 + t;
        int nr = idx >> 4, cc = (idx & 15) * 4;         // nr = n-row, cc = c-col
        float s = inv[b * NSP + n0 + nr];
        u16x4 o;
        #pragma unroll
        for (int si = 0; si < 4; ++si)
            o[si] = f2bf(tile[(cc + si) * 68 + nr] * s * g1[c0 + cc + si]);
        *(u16x4*)(xnt + (long)(b * NSP + n0 + nr) * CDIM + c0 + cc) = o;
    }
}

// ---------------- 256x256 MFMA GEMM, BK=64, 8-phase schedule (4 phases/K-tile).
// C[b][m][n] = A[m][:].Bt[b][n][:].  EPI: 0 = plain bf16 C (kv GEMM),
// 1 = softmax-over-d epilogue -> qhatT (q GEMM), 2 = +bias +column-ssq (out GEMM).
// LDS: As/Bs[buf(2)][ks-half(2)] planes of [256 rows][32 cols] bf16 (16 KB each,
// contiguous -> linear global_load_lds dest). Per phase: {ds_read subtile ||
// stage 1 half-tile || barrier || lgkmcnt(0) || 16 MFMA (setprio) || barrier}.
// vmcnt(8) twice per K-tile (counted, never 0 until tail). Swizzle chunk^=(row>>1)&3
// (measured 0-conflict in rounds 4/5).
template<int EPI>
__global__ __launch_bounds__(512, 2) void gemm256_kernel(
        const unsigned short* __restrict__ A, const unsigned short* __restrict__ Bt,
        unsigned short* __restrict__ C, const float* __restrict__ bias,
        float* __restrict__ ssq, long bt_bstride, long c_bstride) {
    alignas(16) __shared__ unsigned short As[4][8192];   // [buf*2+h][256*32]
    alignas(16) __shared__ unsigned short Bs[4][8192];
    const int t = threadIdx.x, lane = t & 63;
    const int l15 = lane & 15, quad = lane >> 4;
    const int wave = t >> 6, wr = wave >> 2, wc = wave & 3;   // 2 x 4 wave grid
    const int m0 = blockIdx.y * 256, n0 = blockIdx.x * 256, b = blockIdx.z;
    const unsigned short* Bb = Bt + (long)b * bt_bstride;
    const int qsw = (quad ^ ((l15 >> 1) & 3)) * 8;       // swizzled read chunk (shorts)

    // staging addresses: 16B-chunk idx = is*512+t; row = idx>>2; cq = idx&3;
    // source col chunk = cq ^ ((row>>1)&3) (inverse swizzle; LDS dest linear)
    const unsigned short* aSrc[2];
    const unsigned short* bSrc[2];
    int wb[2];
    #pragma unroll
    for (int is = 0; is < 2; ++is) {
        int idx = is * 512 + t;
        int row = idx >> 2, cq = idx & 3;
        int sc = (cq ^ ((row >> 1) & 3)) * 8;
        aSrc[is] = A  + (long)(m0 + row) * GK + sc;
        bSrc[is] = Bb + (long)(n0 + row) * GK + sc;
        wb[is] = (is * 512 + (t & 448)) * 8;             // wave-uniform LDS base (shorts)
    }

    f32x4 acc[8][4] = {};
    s16x8 af[4], bfv[4];

#define STAGE2(srcArr_, dst_, koff_)                                  \
    { _Pragma("unroll")                                               \
      for (int is_ = 0; is_ < 2; ++is_)                               \
          gload16(srcArr_[is_] + (koff_), (dst_) + wb[is_]); }

#define DSA(buf_, ks_, ih_)                                           \
    { const unsigned short* Ap_ = &As[(buf_) * 2 + (ks_)][0];         \
      _Pragma("unroll")                                               \
      for (int ii_ = 0; ii_ < 4; ++ii_)                               \
          af[ii_] = *(const s16x8*)(Ap_ + (wr * 128 + ((ih_) * 4 + ii_) * 16 + l15) * 32 + qsw); }

#define DSB(buf_, ks_)                                                \
    { const unsigned short* Bp_ = &Bs[(buf_) * 2 + (ks_)][0];         \
      _Pragma("unroll")                                               \
      for (int jj_ = 0; jj_ < 4; ++jj_)                               \
          bfv[jj_] = *(const s16x8*)(Bp_ + (wc * 64 + jj_ * 16 + l15) * 32 + qsw); }

#define MM16(ih_)                                                     \
    __builtin_amdgcn_s_setprio(1);                                    \
    _Pragma("unroll")                                                 \
    for (int ii_ = 0; ii_ < 4; ++ii_)                                 \
        _Pragma("unroll")                                             \
        for (int jj_ = 0; jj_ < 4; ++jj_)                             \
            acc[(ih_) * 4 + ii_][jj_] = __builtin_amdgcn_mfma_f32_16x16x32_bf16( \
                af[ii_], bfv[jj_], acc[(ih_) * 4 + ii_][jj_], 0, 0, 0); \
    __builtin_amdgcn_s_setprio(0)

    // prologue: stage A/B h0(0), h1(0), h0(1) = 6 half-tiles (12 loads/thread)
    STAGE2(aSrc, &As[0][0], 0);          // A-h0(0)
    STAGE2(bSrc, &Bs[0][0], 0);          // B-h0(0)
    STAGE2(aSrc, &As[1][0], 32);         // A-h1(0)
    STAGE2(bSrc, &Bs[1][0], 32);         // B-h1(0)
    STAGE2(aSrc, &As[2][0], 64);         // A-h0(1)
    STAGE2(bSrc, &Bs[2][0], 64);         // B-h0(1)
    VMW(8);                              // h0(0) A+B landed (4 halves may remain in flight)
    BARR();

    #pragma unroll 2
    for (int kt = 0; kt < 6; ++kt) {
        const int cb = kt & 1, nb = cb ^ 1;
        // P0: ks0, i0-3; stage A-h1(kt+1)
        DSA(cb, 0, 0); DSB(cb, 0);
        STAGE2(aSrc, &As[nb * 2 + 1][0], (kt + 1) * 64 + 32);
        BARR(); LGKM0(); MM16(0); BARR();
        // P1: ks0, i4-7; stage B-h1(kt+1); confirm h1(kt) for P2/P3
        DSA(cb, 0, 1);
        STAGE2(bSrc, &Bs[nb * 2 + 1][0], (kt + 1) * 64 + 32);
        VMW(8);
        BARR(); LGKM0(); MM16(1); BARR();
        // P2: ks1, i0-3; stage A-h0(kt+2)
        DSA(cb, 1, 0); DSB(cb, 1);
        STAGE2(aSrc, &As[cb * 2 + 0][0], (kt + 2) * 64);
        BARR(); LGKM0(); MM16(0); BARR();
        // P3: ks1, i4-7; stage B-h0(kt+2); confirm h0(kt+1) for next P0/P1
        DSA(cb, 1, 1);
        STAGE2(bSrc, &Bs[cb * 2 + 0][0], (kt + 2) * 64);
        VMW(8);
        BARR(); LGKM0(); MM16(1); BARR();
    }
    // kt = 6 (cb=0, nb=1): kt+2 out of range -> skip those stages, tail vmcnt(4)
    DSA(0, 0, 0); DSB(0, 0);
    STAGE2(aSrc, &As[3][0], 7 * 64 + 32);   // A-h1(7)
    BARR(); LGKM0(); MM16(0); BARR();
    DSA(0, 0, 1);
    STAGE2(bSrc, &Bs[3][0], 7 * 64 + 32);   // B-h1(7)
    VMW(8);
    BARR(); LGKM0(); MM16(1); BARR();
    DSA(0, 1, 0); DSB(0, 1);
    BARR(); LGKM0(); MM16(0); BARR();
    DSA(0, 1, 1);
    VMW(4);                                  // force h0(7) landed (A-h1(7),B-h1(7) may fly)
    BARR(); LGKM0(); MM16(1); BARR();
    // kt = 7 (cb=1): no staging
    DSA(1, 0, 0); DSB(1, 0);
    BARR(); LGKM0(); MM16(0); BARR();
    DSA(1, 0, 1);
    VMW(0);                                  // drain: h1(7) landed for P2/P3
    BARR(); LGKM0(); MM16(1); BARR();
    DSA(1, 1, 0); DSB(1, 1);
    BARR(); LGKM0(); MM16(0); BARR();
    DSA(1, 1, 1);
    LGKM0(); MM16(1);

#undef STAGE2
#undef DSA
#undef DSB
#undef MM16

    if (EPI == 0) {
        unsigned short* Cb = C + (long)b * c_bstride;
        #pragma unroll
        for (int i = 0; i < 8; ++i)
            #pragma unroll
            for (int r = 0; r < 4; ++r) {
                int row = m0 + wr * 128 + i * 16 + quad * 4 + r;
                #pragma unroll
                for (int j = 0; j < 4; ++j)
                    Cb[(long)row * NSP + n0 + wc * 64 + j * 16 + l15] = f2bf(acc[i][j][r]);
            }
    } else if (EPI == 1) {
        // softmax over d within each head's 64 rows, *0.125, write d-contiguous qhatT
        const int hbase = (m0 + wr * 128) >> 6;
        #pragma unroll
        for (int j = 0; j < 4; ++j) {
            int col = n0 + wc * 64 + j * 16 + l15;
            #pragma unroll
            for (int ih = 0; ih < 2; ++ih) {
                float mx = -3.4e38f;
                #pragma unroll
                for (int ii = 0; ii < 4; ++ii)
                    #pragma unroll
                    for (int r = 0; r < 4; ++r) mx = fmaxf(mx, acc[ih * 4 + ii][j][r]);
                mx = fmaxf(mx, __shfl_xor(mx, 16));
                mx = fmaxf(mx, __shfl_xor(mx, 32));
                float sm = 0.f;
                #pragma unroll
                for (int ii = 0; ii < 4; ++ii)
                    #pragma unroll
                    for (int r = 0; r < 4; ++r) {
                        float p = __expf(acc[ih * 4 + ii][j][r] - mx);
                        acc[ih * 4 + ii][j][r] = p;
                        sm += p;
                    }
                sm += __shfl_xor(sm, 16);
                sm += __shfl_xor(sm, 32);
                float rsc = 0.125f / sm;
                unsigned short* op = C + ((long)(b * 8 + hbase + ih) * NSP + col) * 64 + quad * 4;
                #pragma unroll
                for (int ii = 0; ii < 4; ++ii) {
                    u16x4 o;
                    #pragma unroll
                    for (int r = 0; r < 4; ++r) o[r] = f2bf(acc[ih * 4 + ii][j][r] * rsc);
                    *(u16x4*)(op + ii * 16) = o;
                }
            }
        }
    } else {
        unsigned short* Cb = C + (long)b * c_bstride;
        #pragma unroll
        for (int i = 0; i < 8; ++i)
            #pragma unroll
            for (int r = 0; r < 4; ++r) {
                float bv = bias[m0 + wr * 128 + i * 16 + quad * 4 + r];
                #pragma unroll
                for (int j = 0; j < 4; ++j) acc[i][j][r] += bv;
            }
        #pragma unroll
        for (int i = 0; i < 8; ++i)
            #pragma unroll
            for (int r = 0; r < 4; ++r) {
                int row = m0 + wr * 128 + i * 16 + quad * 4 + r;
                #pragma unroll
                for (int j = 0; j < 4; ++j)
                    Cb[(long)row * NSP + n0 + wc * 64 + j * 16 + l15] = f2bf(acc[i][j][r]);
            }
        float* sb = ssq + (long)b * NSP;
        #pragma unroll
        for (int j = 0; j < 4; ++j) {
            float p = 0.f;
            #pragma unroll
            for (int i = 0; i < 8; ++i)
                #pragma unroll
                for (int r = 0; r < 4; ++r) p += acc[i][j][r] * acc[i][j][r];
            p += __shfl_xor(p, 16);
            p += __shfl_xor(p, 32);
            if (quad == 0) atomicAdd(sb + n0 + wc * 64 + j * 16 + l15, p);
        }
    }
}

// ---------------- k softmax stats per (b,row): max, 1/sum(exp)
__global__ __launch_bounds__(256) void kstats_k(const unsigned short* __restrict__ kv,
                                                float* __restrict__ kst) {
    __shared__ float red[8];
    int row = blockIdx.x, b = blockIdx.y, t = threadIdx.x;
    int wave = t >> 6, lane = t & 63;
    const unsigned short* base = kv + ((long)b * 1024 + row) * NSP;
    float v[16];
    u16x8 a0 = *(const u16x8*)(base + t * 16);
    u16x8 a1 = *(const u16x8*)(base + t * 16 + 8);
    #pragma unroll
    for (int e = 0; e < 8; ++e) { v[e] = bf2f(a0[e]); v[8 + e] = bf2f(a1[e]); }
    float mx = v[0];
    #pragma unroll
    for (int e = 1; e < 16; ++e) mx = fmaxf(mx, v[e]);
    #pragma unroll
    for (int off = 32; off; off >>= 1) mx = fmaxf(mx, __shfl_xor(mx, off));
    if (lane == 0) red[wave] = mx;
    __syncthreads();
    mx = fmaxf(fmaxf(red[0], red[1]), fmaxf(red[2], red[3]));
    float sm = 0.f;
    #pragma unroll
    for (int e = 0; e < 16; ++e) sm += __expf(v[e] - mx);
    #pragma unroll
    for (int off = 32; off; off >>= 1) sm += __shfl_xor(sm, off);
    if (lane == 0) red[4 + wave] = sm;
    __syncthreads();
    if (t == 0) {
        float s = red[4] + red[5] + red[6] + red[7];
        kst[((long)b * 512 + row) * 2]     = mx;
        kst[((long)b * 512 + row) * 2 + 1] = 1.f / s;
    }
}

// ---------------- ctxP[slice][bh][e*64+d] = sum_{n in slice} khat[d,n]*v[e,n]
__global__ __launch_bounds__(256, 2) void context_kernel(const unsigned short* __restrict__ kv,
                                                         const float* __restrict__ kst,
                                                         float* __restrict__ ctxP) {
    alignas(16) __shared__ unsigned short Ks[64 * 256];   // 32 KB, swizzled
    alignas(16) __shared__ unsigned short Vs[64 * 256];   // 32 KB, swizzled
    int bh = blockIdx.x, b = bh >> 3, h = bh & 7;
    int t = threadIdx.x, wave = t >> 6, lane = t & 63, l15 = lane & 15, quad = lane >> 4;
    const unsigned short* kp = kv + ((long)b * 1024 + h * 64) * NSP;
    const unsigned short* vp = kv + ((long)b * 1024 + 512 + h * 64) * NSP;
    float mxu[8], rsu[8];
    #pragma unroll
    for (int u = 0; u < 8; ++u) {
        int row = u * 8 + (t >> 5);
        mxu[u] = kst[((long)b * 512 + h * 64 + row) * 2];
        rsu[u] = kst[((long)b * 512 + h * 64 + row) * 2 + 1];
    }
    f32x4 acc[4] = {};
    for (int tile = 0; tile < 4; ++tile) {
        int n0 = blockIdx.y * 1024 + tile * 256;
        #pragma unroll
        for (int is = 0; is < 8; ++is) {
            int cidx = (wave * 8 + is) * 64 + lane;       // 16B-chunk index 0..2047
            int row = cidx >> 5, cq = cidx & 31;
            int sc = (cq ^ (row & 7)) * 8;                // shorts
            gload16(kp + (long)row * NSP + n0 + sc, Ks + (wave * 8 + is) * 512);
            gload16(vp + (long)row * NSP + n0 + sc, Vs + (wave * 8 + is) * 512);
        }
        __syncthreads();
        #pragma unroll
        for (int u = 0; u < 8; ++u) {
            unsigned short* p = Ks + ((u * 256 + t) * 8);
            u16x8 v = *(const u16x8*)p;
            u16x8 o;
            #pragma unroll
            for (int e = 0; e < 8; ++e)
                o[e] = f2bf(__expf(bf2f(v[e]) - mxu[u]) * rsu[u]);
            *(u16x8*)p = o;
        }
        __syncthreads();
        #pragma unroll
        for (int ks = 0; ks < 8; ++ks) {
            s16x8 af[4], bfr;
            #pragma unroll
            for (int i = 0; i < 4; ++i) {
                int row = i * 16 + l15;
                af[i] = *(const s16x8*)(Ks + row * 256 + (((ks * 4 + quad) ^ (row & 7)) * 8));
            }
            {
                int row = wave * 16 + l15;
                bfr = *(const s16x8*)(Vs + row * 256 + (((ks * 4 + quad) ^ (row & 7)) * 8));
            }
            #pragma unroll
            for (int i = 0; i < 4; ++i)
                acc[i] = __builtin_amdgcn_mfma_f32_16x16x32_bf16(af[i], bfr, acc[i], 0, 0, 0);
        }
        __syncthreads();
    }
    float* cp = ctxP + ((long)blockIdx.y * 128 + bh) * 4096;
    #pragma unroll
    for (int i = 0; i < 4; ++i)
        *(f32x4*)(cp + (wave * 16 + l15) * 64 + i * 16 + quad * 4) = acc[i];
}

// ---------------- ctxT = sum over slices of ctxP
__global__ __launch_bounds__(256) void ctxreduce_k(const float* __restrict__ ctxP,
                                                   float* __restrict__ ctxT) {
    long i = ((long)blockIdx.x * 256 + threadIdx.x) * 4;
    f32x4 s = *(const f32x4*)(ctxP + i);
    #pragma unroll
    for (int sl = 1; sl < CTX_SLICES; ++sl) {
        f32x4 v = *(const f32x4*)(ctxP + (long)sl * 128 * 4096 + i);
        s += v;
    }
    *(f32x4*)(ctxT + i) = s;
}

// ---------------- attnT[b][n][h*64+e] = sum_d ctxT[e][d]*qhatT[n][d]   (MFMA)
__global__ __launch_bounds__(256) void attnout_kernel(const float* __restrict__ ctxT,
                                                      const unsigned short* __restrict__ qhatT,
                                                      unsigned short* __restrict__ attnT) {
    int bh = blockIdx.x, b = bh >> 3, h = bh & 7;
    int t = threadIdx.x, wave = t >> 6, lane = t & 63, l15 = lane & 15, quad = lane >> 4;
    int n0 = blockIdx.y * 256 + wave * 64;
    const float* cb = ctxT + (long)bh * 4096;
    s16x8 af[2][4];
    #pragma unroll
    for (int ks = 0; ks < 2; ++ks)
        #pragma unroll
        for (int i = 0; i < 4; ++i) {
            const float* src = cb + (i * 16 + l15) * 64 + ks * 32 + quad * 8;
            s16x8 a;
            #pragma unroll
            for (int e = 0; e < 8; ++e) a[e] = (short)f2bf(src[e]);
            af[ks][i] = a;
        }
    f32x4 acc[4][4] = {};
    const unsigned short* qb = qhatT + (long)bh * NSP * 64;
    #pragma unroll
    for (int ks = 0; ks < 2; ++ks) {
        s16x8 bfr[4];
        #pragma unroll
        for (int j = 0; j < 4; ++j)
            bfr[j] = *(const s16x8*)(qb + (long)(n0 + j * 16 + l15) * 64 + ks * 32 + quad * 8);
        #pragma unroll
        for (int i = 0; i < 4; ++i)
            #pragma unroll
            for (int j = 0; j < 4; ++j)
                acc[i][j] = __builtin_amdgcn_mfma_f32_16x16x32_bf16(af[ks][i], bfr[j], acc[i][j], 0, 0, 0);
    }
    #pragma unroll
    for (int i = 0; i < 4; ++i)
        #pragma unroll
        for (int j = 0; j < 4; ++j) {
            int n = n0 + j * 16 + l15;
            u16x4 o;
            #pragma unroll
            for (int r = 0; r < 4; ++r) o[r] = f2bf(acc[i][j][r]);
            *(u16x4*)(attnT + ((long)b * NSP + n) * CDIM + h * 64 + i * 16 + quad * 4) = o;
        }
}

// ---------------- out fp32 = y_bf16 * (SQRTC*rsqrt(ssq[b,n])) * g2[c]
__global__ __launch_bounds__(256) void final_kernel(const unsigned short* __restrict__ y,
                                                    const float* __restrict__ g2,
                                                    const float* __restrict__ ssq,
                                                    float* __restrict__ out) {
    long flat = ((long)blockIdx.x * 256 + threadIdx.x) * 4;
    int b = (int)(flat >> 21);
    int rem = (int)(flat & ((1 << 21) - 1));
    int c = rem >> 12, n = rem & 4095;
    u16x4 u = *(const u16x4*)(y + flat);
    f32x4 sq = *(const f32x4*)(ssq + b * NSP + n);
    float g = g2[c];
    f32x4 ov;
    #pragma unroll
    for (int s = 0; s < 4; ++s)
        ov[s] = bf2f(u[s]) * (SQRTC * rsqrtf(fmaxf(sq[s], 1e-24f))) * g;
    *(f32x4*)(out + flat) = ov;
}

extern "C" void kernel_launch(void* const* d_in, const int* in_sizes, int n_in,
                              void* d_out, int out_size, void* d_ws, size_t ws_size,
                              hipStream_t stream) {
    (void)in_sizes; (void)n_in; (void)out_size; (void)ws_size;
    const float* x     = (const float*)d_in[0];
    const float* g1    = (const float*)d_in[1];
    const float* w_qkv = (const float*)d_in[2];
    const float* w_out = (const float*)d_in[3];
    const float* b_out = (const float*)d_in[4];
    const float* g2    = (const float*)d_in[5];
    float* out = (float*)d_out;

    char* ws = (char*)d_ws;
    const size_t MB = 1024 * 1024;
    // [0,64): xnt -> attnT.  [64,192): kv; y reuses [64,128), qhatT at [128,192).
    unsigned short* xnt   = (unsigned short*)(ws);
    unsigned short* attnT = xnt;
    unsigned short* kv    = (unsigned short*)(ws + 64 * MB);
    unsigned short* y     = kv;
    unsigned short* qhatT = (unsigned short*)(ws + 128 * MB);
    unsigned short* wqkvb = (unsigned short*)(ws + 192 * MB);            // 1.5 MiB
    unsigned short* woutb = (unsigned short*)(ws + 192 * MB + 1536 * 1024); // 0.5 MiB
    float* inv1 = (float*)(ws + 194 * MB);
    float* ssq  = (float*)(ws + 194 * MB + 256 * 1024);                  // 256 KB
    float* kst  = (float*)(ws + 194 * MB + 512 * 1024);
    float* ctxT = (float*)(ws + 195 * MB);                               // 2 MiB
    float* ctxP = (float*)(ws + 197 * MB);                               // 8 MiB -> ends 205 MiB

    hipLaunchKernelGGL(convert_k, dim3(768), dim3(256), 0, stream, w_qkv, wqkvb, 196608);
    hipLaunchKernelGGL(convert_k, dim3(256), dim3(256), 0, stream, w_out, woutb, 65536);
    hipMemsetAsync(ssq, 0, (size_t)B_ * NSP * 4, stream);
    hipLaunchKernelGGL(inv_stats_x_k, dim3(64, 16), dim3(256), 0, stream, x, inv1);
    hipLaunchKernelGGL(xnt_kernel, dim3(64, 8, 16), dim3(256), 0, stream, x, g1, inv1, xnt);
    // kv GEMM: rows 512..1535 of wqkvb, M=1024
    hipLaunchKernelGGL((gemm256_kernel<0>), dim3(16, 4, 16), dim3(512), 0, stream,
                       wqkvb + 512 * GK, xnt, kv, (const float*)nullptr, (float*)nullptr,
                       (long)NSP * CDIM, (long)1024 * NSP);
    hipLaunchKernelGGL(kstats_k, dim3(512, 16), dim3(256), 0, stream, kv, kst);
    hipLaunchKernelGGL(context_kernel, dim3(128, CTX_SLICES), dim3(256), 0, stream, kv, kst, ctxP);
    hipLaunchKernelGGL(ctxreduce_k, dim3(512), dim3(256), 0, stream, ctxP, ctxT);
    // q GEMM (rows 0..511) with fused softmax epilogue -> qhatT
    hipLaunchKernelGGL((gemm256_kernel<1>), dim3(16, 2, 16), dim3(512), 0, stream,
                       wqkvb, xnt, qhatT, (const float*)nullptr, (float*)nullptr,
                       (long)NSP * CDIM, 0L);
    hipLaunchKernelGGL(attnout_kernel, dim3(128, 16), dim3(256), 0, stream, ctxT, qhatT, attnT);
    // out GEMM with bias + fused column-ssq accumulation
    hipLaunchKernelGGL((gemm256_kernel<2>), dim3(16, 2, 16), dim3(512), 0, stream,
                       woutb, attnT, y, b_out, ssq, (long)NSP * CDIM, (long)512 * NSP);
    hipLaunchKernelGGL(final_kernel, dim3(32768), dim3(256), 0, stream, y, g2, ssq, out);
}